// Round 7
// baseline (427.712 us; speedup 1.0000x reference)
//
#include <hip/hip_runtime.h>
#include <hip/hip_bf16.h>
#include <math.h>

// Problem constants (B,S,D) = (4,4096,1024)
#define BDIM 4
#define SDIM 4096
#define DDIM 1024
#define MROWS (BDIM*SDIM)      // 16384
#define EPS 1e-6f
#define NCHUNK 64              // chunks along S
#define LCHUNK 64              // chunk length (NCHUNK*LCHUNK == SDIM)

typedef _Float16 f16_t;
typedef _Float16 f16x2_t __attribute__((ext_vector_type(2)));
typedef _Float16 f16x4_t __attribute__((ext_vector_type(4)));
typedef _Float16 f16x8_t __attribute__((ext_vector_type(8)));     // MFMA A/B frag (4 VGPRs)
typedef float    f32x4_t __attribute__((ext_vector_type(4)));     // MFMA C/D frag

// async global->LDS, 16B per lane (dest = wave-uniform base + lane*16)
__device__ __forceinline__ void gload16(const void* g, void* l) {
    __builtin_amdgcn_global_load_lds(
        (const __attribute__((address_space(1))) unsigned int*)g,
        (__attribute__((address_space(3))) unsigned int*)l, 16, 0, 0);
}

// ---------------------------------------------------------------------------
// Guard-fail fill (encodes ws_size MB as output on too-small workspace)
// ---------------------------------------------------------------------------
__global__ __launch_bounds__(256) void fill_kernel(float* __restrict__ out,
                                                   int n, float val)
{
    const int i = blockIdx.x * 256 + threadIdx.x;
    if (i < n) out[i] = val;
}

// ---------------------------------------------------------------------------
// RMSNorm: one block per row of D=1024; outputs fp16 xn.
// ---------------------------------------------------------------------------
__global__ __launch_bounds__(256) void rmsnorm_kernel(
    const float* __restrict__ x, const float* __restrict__ scale,
    f16_t* __restrict__ xn)
{
    const int row = blockIdx.x;
    const int tid = threadIdx.x;
    const float4 v = reinterpret_cast<const float4*>(x + (size_t)row * DDIM)[tid];
    float ss = v.x*v.x + v.y*v.y + v.z*v.z + v.w*v.w;
    #pragma unroll
    for (int off = 32; off > 0; off >>= 1)
        ss += __shfl_down(ss, off, 64);
    __shared__ float red[4];
    if ((tid & 63) == 0) red[tid >> 6] = ss;
    __syncthreads();
    ss = red[0] + red[1] + red[2] + red[3];
    const float inv = rsqrtf(ss * (1.0f / DDIM) + EPS);
    const float4 sc = reinterpret_cast<const float4*>(scale)[tid];
    f16x4_t o;
    o.x = (f16_t)(v.x * inv * sc.x);
    o.y = (f16_t)(v.y * inv * sc.y);
    o.z = (f16_t)(v.z * inv * sc.z);
    o.w = (f16_t)(v.w * inv * sc.w);
    reinterpret_cast<f16x4_t*>(xn + (size_t)row * DDIM)[tid] = o;
}

// ---------------------------------------------------------------------------
// Merged weight prep (one launch, grid (64,32,4)):
//  z=0: (wq,wg) pair-interleaved -> WT slots 0..1
//  z=1: (wk,wv) pair-interleaved -> WT slots 2..3
//  z=2: wo plain transpose       -> WT slot 6
//  z=3: wa half-interleaved      -> WT slots 4..5
// z<3 use only blockIdx.x<32 (idle blocks exit before any barrier).
// ---------------------------------------------------------------------------
__global__ __launch_bounds__(256) void wprep_kernel(
    const float* __restrict__ wq, const float* __restrict__ wk,
    const float* __restrict__ wv, const float* __restrict__ wa,
    const float* __restrict__ wg, const float* __restrict__ wo,
    f16_t* __restrict__ WT)
{
    const size_t WSZ = (size_t)DDIM * DDIM;
    const int z = blockIdx.z;
    __shared__ float t0[32][33];
    __shared__ float t1[32][33];
    const int kb = blockIdx.y * 32;
    const int r  = threadIdx.x >> 3;
    const int c0 = (threadIdx.x & 7) << 2;

    if (z == 3) {
        // wa: W[K][2048] -> WT[n][K], row n <- col (n>>1) + (n&1)*1024
        const int K = DDIM, N = 2 * DDIM;
        const int nb = blockIdx.x * 32;
        const int base = (c0 < 16) ? ((nb >> 1) + c0) : (DDIM + (nb >> 1) + c0 - 16);
        const float4 v = *reinterpret_cast<const float4*>(&wa[(size_t)(kb + r) * N + base]);
        t0[r][c0 + 0] = v.x; t0[r][c0 + 1] = v.y; t0[r][c0 + 2] = v.z; t0[r][c0 + 3] = v.w;
        __syncthreads();
        const int ctile = (r >> 1) + (r & 1) * 16;
        f16x4_t o;
        o.x = (f16_t)t0[c0 + 0][ctile];
        o.y = (f16_t)t0[c0 + 1][ctile];
        o.z = (f16_t)t0[c0 + 2][ctile];
        o.w = (f16_t)t0[c0 + 3][ctile];
        *reinterpret_cast<f16x4_t*>(&WT[4 * WSZ + (size_t)(nb + r) * K + kb + c0]) = o;
        return;
    }
    if (blockIdx.x >= 32) return;
    const int nb = blockIdx.x * 32;
    const int K = DDIM, N = DDIM;
    if (z == 2) {
        // wo plain transpose -> slot 6
        const float4 v = *reinterpret_cast<const float4*>(&wo[(size_t)(kb + r) * N + nb + c0]);
        t0[r][c0 + 0] = v.x; t0[r][c0 + 1] = v.y; t0[r][c0 + 2] = v.z; t0[r][c0 + 3] = v.w;
        __syncthreads();
        f16x4_t o;
        o.x = (f16_t)t0[c0 + 0][r];
        o.y = (f16_t)t0[c0 + 1][r];
        o.z = (f16_t)t0[c0 + 2][r];
        o.w = (f16_t)t0[c0 + 3][r];
        *reinterpret_cast<f16x4_t*>(&WT[6 * WSZ + (size_t)(nb + r) * K + kb + c0]) = o;
        return;
    }
    // z=0/1: pair-interleave (W0,W1): WT[2n][k]=W0[k][n], WT[2n+1][k]=W1[k][n]
    const float* W0 = (z == 0) ? wq : wk;
    const float* W1 = (z == 0) ? wg : wv;
    f16_t* dst = WT + (size_t)(z * 2) * WSZ;
    const float4 v0 = *reinterpret_cast<const float4*>(&W0[(size_t)(kb + r) * N + nb + c0]);
    const float4 v1 = *reinterpret_cast<const float4*>(&W1[(size_t)(kb + r) * N + nb + c0]);
    t0[r][c0 + 0] = v0.x; t0[r][c0 + 1] = v0.y; t0[r][c0 + 2] = v0.z; t0[r][c0 + 3] = v0.w;
    t1[r][c0 + 0] = v1.x; t1[r][c0 + 1] = v1.y; t1[r][c0 + 2] = v1.z; t1[r][c0 + 3] = v1.w;
    __syncthreads();
    const int rr  = threadIdx.x >> 2;        // output row in block: 0..63
    const int cc0 = (threadIdx.x & 3) << 3;  // 0,8,16,24
    const int n   = rr >> 1;                 // source col within tile
    f16x8_t o;
    if (rr & 1) {
        #pragma unroll
        for (int e = 0; e < 8; ++e) o[e] = (f16_t)t1[cc0 + e][n];
    } else {
        #pragma unroll
        for (int e = 0; e < 8; ++e) o[e] = (f16_t)t0[cc0 + e][n];
    }
    *reinterpret_cast<f16x8_t*>(&dst[(size_t)(2 * nb + rr) * K + kb + cc0]) = o;
}

// ---------------------------------------------------------------------------
// fp16 MFMA GEMM (m97 pattern, R4-proven core): C[M,N] = A[M,K] @ BT[N,K]^T
// 128x128 tile, BK=32, 256 threads = 4 waves, each wave 64x64 (4x4 MFMA tiles).
//  - T1 XCD-aware bijective block swizzle (R4: FETCH 142->94 MB)
//  - quad-XOR LDS swizzle (R4: bank conflicts 12.6M -> 0)
// MODE 0: C(f32) = A@B  (final GEMM)
// MODE 7: merged projections, N=6144 over WT slots qg|kv|a:
//   bn<2048:       qsg = q*silu(g) -> Cv   (pairs; LDS-staged full-line write)
//   2048<=bn<4096: kv  = k*v       -> Cv2  (pairs; LDS-staged full-line write)
//   bn>=4096:      a-polar fused   -> Cv3  (direct; row stride 2048)
// Pair regions: adjacent lanes hold (X=even col, Y=odd col); even lane keeps
// the product. Staging into LDS[128][68] then 128B line-aligned row copies
// eliminates partial-line write-allocate fetches (R6: FETCH 94->200 MB).
// ---------------------------------------------------------------------------
template <int MODE>
__global__ __launch_bounds__(256, 2) void mfma_gemm_kernel(
    const f16_t* __restrict__ A, const f16_t* __restrict__ BT,
    void* __restrict__ Cv, void* __restrict__ Cv2, void* __restrict__ Cv3,
    int M, int N, int K)
{
    // smem: K-loop uses [0..4095]=As, [4096..8191]=Bs (each 128x32 f16).
    // MODE-7 pair epilogue reuses it as [128][68] f16 (stride 68 spreads
    // the 4-row-spaced group writes across distinct bank quads).
    __shared__ __align__(16) f16_t smem[128 * 68];
    f16_t* As = smem;
    f16_t* Bs = smem + 128 * 32;

    const int tid  = threadIdx.x;
    const int wave = tid >> 6;
    const int lane = tid & 63;

    // ---- T1: XCD-aware bijective block swizzle ---------------------------
    const int gx  = gridDim.x;
    const int nwg = gx * gridDim.y;
    const int lid = blockIdx.y * gx + blockIdx.x;
    const int cpx = nwg >> 3;                  // nwg % 8 == 0 for all grids
    const int vid = (lid & 7) * cpx + (lid >> 3);
    const int bm = (vid / gx) * 128;
    const int bn = (vid % gx) * 128;

    const int wm = (wave & 1) * 64;
    const int wn = (wave >> 1) * 64;

    // ---- staging: quad-contiguous, within-quad chunk XOR -----------------
    const int sr = tid >> 2;
    const int sc = (((tid & 3) ^ ((tid >> 3) & 3)) << 3);   // swizzled chunk
    const f16_t* Ag = A  + (size_t)(bm + sr) * K + sc;
    const f16_t* Bg = BT + (size_t)(bn + sr) * K + sc;
    f16_t* Al0 = As + tid * 8;
    f16_t* Al1 = As + 64 * 32 + tid * 8;
    f16_t* Bl0 = Bs + tid * 8;
    f16_t* Bl1 = Bs + 64 * 32 + tid * 8;
    const size_t rowskip = (size_t)64 * K;

    f32x4_t acc[4][4] = {};

    // ---- frag read: same XOR key ((row>>1)&3 == (lane>>1)&3) -------------
    const int fm = lane & 15;
    const int kh = (((lane >> 4) ^ ((lane >> 1) & 3)) << 3);

    for (int kt = 0; kt < K; kt += 32) {
        gload16(Ag + kt, Al0);
        gload16(Ag + rowskip + kt, Al1);
        gload16(Bg + kt, Bl0);
        gload16(Bg + rowskip + kt, Bl1);
        __syncthreads();

        f16x8_t af[4], bfr[4];
        #pragma unroll
        for (int i = 0; i < 4; ++i)
            af[i] = *reinterpret_cast<const f16x8_t*>(&As[(wm + i * 16 + fm) * 32 + kh]);
        #pragma unroll
        for (int j = 0; j < 4; ++j)
            bfr[j] = *reinterpret_cast<const f16x8_t*>(&Bs[(wn + j * 16 + fm) * 32 + kh]);
        #pragma unroll
        for (int i = 0; i < 4; ++i)
            #pragma unroll
            for (int j = 0; j < 4; ++j)
                acc[i][j] = __builtin_amdgcn_mfma_f32_16x16x32_f16(
                    af[i], bfr[j], acc[i][j], 0, 0, 0);
        __syncthreads();
    }

    // epilogue: D row=(lane>>4)*4+reg, col=lane&15  (m89/m91-verified)
    const int erow = (lane >> 4) << 2;
    const int ecol = lane & 15;

    if (MODE == 7 && bn < 4096) {
        // ---- pair-product regions: stage to LDS, full-line copy out ------
        const bool isQ = (bn < 2048);
        #pragma unroll
        for (int i = 0; i < 4; ++i) {
            #pragma unroll
            for (int j = 0; j < 4; ++j) {
                #pragma unroll
                for (int rg = 0; rg < 4; ++rg) {
                    const float val = acc[i][j][rg];
                    const float par = __shfl_xor(val, 1, 64);
                    if (!(lane & 1)) {
                        const float X = val, Y = par;
                        const float outv = isQ ? X * (Y / (1.0f + __expf(-Y)))
                                               : X * Y;
                        smem[(wm + i * 16 + erow + rg) * 68
                             + (wn >> 1) + j * 8 + (ecol >> 1)] = (f16_t)outv;
                    }
                }
            }
        }
        __syncthreads();
        f16_t* dstb = isQ ? (f16_t*)Cv : (f16_t*)Cv2;
        const int prow = tid >> 1;
        const int phal = (tid & 1) * 32;
        const f16_t* src = smem + prow * 68 + phal;
        f16_t* d = dstb + (size_t)(bm + prow) * DDIM + ((bn & 2047) >> 1) + phal;
        #pragma unroll
        for (int q = 0; q < 4; ++q)
            *reinterpret_cast<f16x8_t*>(d + q * 8) =
                *reinterpret_cast<const f16x8_t*>(src + q * 8);
        return;
    }

    #pragma unroll
    for (int i = 0; i < 4; ++i) {
        #pragma unroll
        for (int j = 0; j < 4; ++j) {
            const int row0 = bm + wm + i * 16 + erow;
            const int col  = bn + wn + j * 16 + ecol;
            #pragma unroll
            for (int rg = 0; rg < 4; ++rg) {
                const float val = acc[i][j][rg];
                if (MODE == 0) {
                    ((float*)Cv)[(size_t)(row0 + rg) * N + col] = val;
                } else {  // MODE 7, a-polar region (bn >= 4096)
                    const float par = __shfl_xor(val, 1, 64);
                    const float re = (lane & 1) ? par : val;
                    const float im = (lane & 1) ? val : par;
                    const float r = sqrtf(re * re + im * im);
                    float outv;
                    if (r > 0.0f) {
                        const float sg = 1.0f / (1.0f + __expf(-r));
                        outv = val * (sg / r);
                    } else {
                        outv = (lane & 1) ? 0.0f : 0.5f;
                    }
                    ((f16_t*)Cv3)[(size_t)(row0 + rg) * (2 * DDIM)
                                  + (col - 4096)] = (f16_t)outv;
                }
            }
        }
    }
}

// ---------------------------------------------------------------------------
// Scan phase 1 (x2 channels/thread): per-(b,chunk,d-pair) local scan;
// emit (A_prod, H_local) float4 per channel. a layout: [m][d] f16x2 (re,im).
// ---------------------------------------------------------------------------
__global__ __launch_bounds__(256) void scan1_kernel(
    const f16x2_t* __restrict__ a2, const f16_t* __restrict__ kvb,
    float4* __restrict__ state)
{
    const int t = blockIdx.x * 256 + threadIdx.x;   // B*NCHUNK*512
    const int d2 = (t & 511) << 1;
    const int c = (t >> 9) & (NCHUNK - 1);
    const int b = t >> 15;
    size_t base  = ((size_t)(b * SDIM + c * LCHUNK)) * DDIM + d2;
    float Ar0 = 1.0f, Ai0 = 0.0f, Hr0 = 0.0f, Hi0 = 0.0f;
    float Ar1 = 1.0f, Ai1 = 0.0f, Hr1 = 0.0f, Hi1 = 0.0f;
    for (int s = 0; s < LCHUNK; ++s) {
        const f16x4_t av = *reinterpret_cast<const f16x4_t*>(&a2[base]);   // 2 ch
        const f16x2_t kv2 = *reinterpret_cast<const f16x2_t*>(&kvb[base]);
        {
            const float ar = (float)av.x, ai = (float)av.y, kv = (float)kv2.x;
            const float hr = ar * Hr0 - ai * Hi0 + kv;
            const float hi = ar * Hi0 + ai * Hr0;
            Hr0 = hr; Hi0 = hi;
            const float nr = ar * Ar0 - ai * Ai0;
            const float ni = ar * Ai0 + ai * Ar0;
            Ar0 = nr; Ai0 = ni;
        }
        {
            const float ar = (float)av.z, ai = (float)av.w, kv = (float)kv2.y;
            const float hr = ar * Hr1 - ai * Hi1 + kv;
            const float hi = ar * Hi1 + ai * Hr1;
            Hr1 = hr; Hi1 = hi;
            const float nr = ar * Ar1 - ai * Ai1;
            const float ni = ar * Ai1 + ai * Ar1;
            Ar1 = nr; Ai1 = ni;
        }
        base += DDIM;
    }
    const size_t st = ((size_t)(b * NCHUNK + c)) * DDIM + d2;
    state[st]     = make_float4(Ar0, Ai0, Hr0, Hi0);
    state[st + 1] = make_float4(Ar1, Ai1, Hr1, Hi1);
}

// ---------------------------------------------------------------------------
// Scan phase 2: wave-parallel chunk combine. Lane c holds chunk c's state;
// 6-step Hillis-Steele inclusive scan of (A,H)∘, then exclusive-shift -> carry.
// ---------------------------------------------------------------------------
__global__ __launch_bounds__(256) void scan2_kernel(
    const float4* __restrict__ state, float2* __restrict__ carry)
{
    const int t = blockIdx.x * 256 + threadIdx.x;   // B*D*64 threads
    const int c = t & 63;            // chunk index = lane
    const int ch = t >> 6;           // channel: b*1024+d
    const int d = ch & 1023;
    const int b = ch >> 10;
    const size_t idx = ((size_t)(b * NCHUNK + c)) * DDIM + d;
    const float4 st = state[idx];
    float Ar = st.x, Ai = st.y, Hr = st.z, Hi = st.w;
    #pragma unroll
    for (int off = 1; off < 64; off <<= 1) {
        const float pAr = __shfl_up(Ar, off, 64);
        const float pAi = __shfl_up(Ai, off, 64);
        const float pHr = __shfl_up(Hr, off, 64);
        const float pHi = __shfl_up(Hi, off, 64);
        if (c >= off) {
            // compose(earlier=(pA,pH), current=(A,H)): A·pA, A·pH + H
            const float nHr = Ar * pHr - Ai * pHi + Hr;
            const float nHi = Ar * pHi + Ai * pHr + Hi;
            const float nAr = Ar * pAr - Ai * pAi;
            const float nAi = Ar * pAi + Ai * pAr;
            Ar = nAr; Ai = nAi; Hr = nHr; Hi = nHi;
        }
    }
    // exclusive prefix: carry into chunk c = inclusive H at chunk c-1
    const float eHr = __shfl_up(Hr, 1, 64);
    const float eHi = __shfl_up(Hi, 1, 64);
    carry[idx] = make_float2(c == 0 ? 0.0f : eHr, c == 0 ? 0.0f : eHi);
}

// ---------------------------------------------------------------------------
// Scan phase 3 (x2 channels/thread): re-scan with carry;
// y(f16) = qsg * Re(h), written IN-PLACE over kv.  (qsg = q*silu(g), fused
// in the merged GEMM epilogue.)
// ---------------------------------------------------------------------------
__global__ __launch_bounds__(256) void scan3_kernel(
    const f16x2_t* __restrict__ a2, f16_t* __restrict__ kvb,
    const f16_t* __restrict__ qsgb, const float2* __restrict__ carry)
{
    const int t = blockIdx.x * 256 + threadIdx.x;   // B*NCHUNK*512
    const int d2 = (t & 511) << 1;
    const int c = (t >> 9) & (NCHUNK - 1);
    const int b = t >> 15;
    size_t base  = ((size_t)(b * SDIM + c * LCHUNK)) * DDIM + d2;
    const size_t st = ((size_t)(b * NCHUNK + c)) * DDIM + d2;
    const float2 h0a = carry[st];
    const float2 h0b = carry[st + 1];
    float Hr0 = h0a.x, Hi0 = h0a.y;
    float Hr1 = h0b.x, Hi1 = h0b.y;
    for (int s = 0; s < LCHUNK; ++s) {
        const f16x4_t av = *reinterpret_cast<const f16x4_t*>(&a2[base]);
        const f16x2_t kv2 = *reinterpret_cast<const f16x2_t*>(&kvb[base]);
        const f16x2_t qs2 = *reinterpret_cast<const f16x2_t*>(&qsgb[base]);
        f16x2_t y;
        {
            const float ar = (float)av.x, ai = (float)av.y, kv = (float)kv2.x;
            const float hr = ar * Hr0 - ai * Hi0 + kv;
            const float hi = ar * Hi0 + ai * Hr0;
            Hr0 = hr; Hi0 = hi;
            y.x = (f16_t)((float)qs2.x * hr);
        }
        {
            const float ar = (float)av.z, ai = (float)av.w, kv = (float)kv2.y;
            const float hr = ar * Hr1 - ai * Hi1 + kv;
            const float hi = ar * Hi1 + ai * Hr1;
            Hr1 = hr; Hi1 = hi;
            y.y = (f16_t)((float)qs2.y * hr);
        }
        *reinterpret_cast<f16x2_t*>(&kvb[base]) = y;
        base += DDIM;
    }
}

// ---------------------------------------------------------------------------
// kernel_launch
//
// Workspace layout (149 MB):
//   xn:  [SZ f16]   33.5MB — A operand; scan `state` (4MB) overlaps after death
//   kv:  [SZ f16]   33.5MB — kv=k*v (fused GEMM), then y (in-place in scan3)
//   a:   [SZ f16x2] 67MB   — interleaved (re,im) channel pairs
//   WT:  [7*WSZ f16] 14MB  — slots: 0..1=qg 2..3=kv 4..5=a (all interleaved),
//        6=o; `carry` (2MB) overlaps dead slot 0 after the projection GEMM
// qsg (f16) lives in the first half of d_out until the final GEMM overwrites it.
// Launches: rmsnorm, wprep, proj-GEMM(N=6144), scan1, scan2, scan3, final GEMM.
// ---------------------------------------------------------------------------
extern "C" void kernel_launch(void* const* d_in, const int* in_sizes, int n_in,
                              void* d_out, int out_size, void* d_ws, size_t ws_size,
                              hipStream_t stream)
{
    const float* x        = (const float*)d_in[0];
    const float* wq       = (const float*)d_in[1];
    const float* wk       = (const float*)d_in[2];
    const float* wv       = (const float*)d_in[3];
    const float* wa       = (const float*)d_in[4];
    const float* wg       = (const float*)d_in[5];
    const float* wo       = (const float*)d_in[6];
    const float* rms_scale= (const float*)d_in[7];
    float* out = (float*)d_out;

    const size_t SZ = (size_t)MROWS * DDIM;   // 16,777,216 elements
    const size_t WSZ = (size_t)DDIM * DDIM;   // 1,048,576
    char* ws = (char*)d_ws;
    f16_t*   xn   = (f16_t*)ws;                        // SZ f16
    f16_t*   kv   = (f16_t*)(ws + SZ * 2);             // SZ f16
    f16x2_t* abuf = (f16x2_t*)(ws + SZ * 4);           // SZ f16x2
    f16_t*   WT   = (f16_t*)(ws + SZ * 8);             // 7*WSZ f16
    f16_t* WTo  = WT + 6 * WSZ;      // slot 6
    float4* state = (float4*)xn;     // overlaps dead xn (4MB)
    float2* carry = (float2*)WT;     // overlaps dead WT slot 0 (2MB)

    f16_t* qsgb = (f16_t*)d_out;     // qsg f16 in first half of d_out

    const size_t needed = SZ * 8 + 7 * WSZ * 2;
    if (ws_size < needed) {
        const float marker = (float)(ws_size >> 20);
        fill_kernel<<<(out_size + 255) / 256, 256, 0, stream>>>(out, out_size, marker);
        return;
    }

    // 1. RMSNorm -> f16 xn
    rmsnorm_kernel<<<MROWS, 256, 0, stream>>>(x, rms_scale, xn);

    // 2. Weight prep (single launch)
    dim3 wgrid(64, 32, 4);
    wprep_kernel<<<wgrid, 256, 0, stream>>>(wq, wk, wv, wa, wg, wo, WT);

    // 3. Merged projection GEMM: N=6144 over WT slots qg|kv|a
    //    -> qsg (d_out), kv=k*v (ws), a-polar (abuf)
    dim3 blk(256);
    dim3 gp(6 * DDIM / 128, MROWS / 128);     // (48,128)
    mfma_gemm_kernel<7><<<gp, blk, 0, stream>>>(xn, WT, qsgb, kv, abuf,
                                                MROWS, 6 * DDIM, DDIM);

    // 4. chunked complex scan (x2-channel vectorized phases 1 & 3)
    const int nscan2 = BDIM * NCHUNK * 512;   // 131072 threads
    const int nscan  = BDIM * NCHUNK * DDIM;  // 262144 threads (phase 2)
    scan1_kernel<<<nscan2 / 256, 256, 0, stream>>>(abuf, kv, state);
    scan2_kernel<<<nscan / 256, 256, 0, stream>>>(state, carry);
    scan3_kernel<<<nscan2 / 256, 256, 0, stream>>>(abuf, kv, qsgb, carry);

    // 5. out = y @ wo   (y lives in kv buffer)
    dim3 g1(DDIM / 128, MROWS / 128);         // (8,128)
    mfma_gemm_kernel<0><<<g1, blk, 0, stream>>>(kv, WTo, out, nullptr, nullptr,
                                                MROWS, DDIM, DDIM);
}

// Round 8
// 419.468 us; speedup vs baseline: 1.0197x; 1.0197x over previous
//
#include <hip/hip_runtime.h>
#include <hip/hip_bf16.h>
#include <math.h>

// Problem constants (B,S,D) = (4,4096,1024)
#define BDIM 4
#define SDIM 4096
#define DDIM 1024
#define MROWS (BDIM*SDIM)      // 16384
#define EPS 1e-6f
#define NCHUNK 64              // chunks along S
#define LCHUNK 64              // chunk length (NCHUNK*LCHUNK == SDIM)

typedef _Float16 f16_t;
typedef _Float16 f16x2_t __attribute__((ext_vector_type(2)));
typedef _Float16 f16x4_t __attribute__((ext_vector_type(4)));
typedef _Float16 f16x8_t __attribute__((ext_vector_type(8)));     // MFMA A/B frag (4 VGPRs)
typedef float    f32x4_t __attribute__((ext_vector_type(4)));     // MFMA C/D frag

// async global->LDS, 16B per lane (dest = wave-uniform base + lane*16)
__device__ __forceinline__ void gload16(const void* g, void* l) {
    __builtin_amdgcn_global_load_lds(
        (const __attribute__((address_space(1))) unsigned int*)g,
        (__attribute__((address_space(3))) unsigned int*)l, 16, 0, 0);
}

// ---------------------------------------------------------------------------
// Guard-fail fill (encodes ws_size MB as output on too-small workspace)
// ---------------------------------------------------------------------------
__global__ __launch_bounds__(256) void fill_kernel(float* __restrict__ out,
                                                   int n, float val)
{
    const int i = blockIdx.x * 256 + threadIdx.x;
    if (i < n) out[i] = val;
}

// ---------------------------------------------------------------------------
// RMSNorm: one block per row of D=1024; outputs fp16 xn.
// ---------------------------------------------------------------------------
__global__ __launch_bounds__(256) void rmsnorm_kernel(
    const float* __restrict__ x, const float* __restrict__ scale,
    f16_t* __restrict__ xn)
{
    const int row = blockIdx.x;
    const int tid = threadIdx.x;
    const float4 v = reinterpret_cast<const float4*>(x + (size_t)row * DDIM)[tid];
    float ss = v.x*v.x + v.y*v.y + v.z*v.z + v.w*v.w;
    #pragma unroll
    for (int off = 32; off > 0; off >>= 1)
        ss += __shfl_down(ss, off, 64);
    __shared__ float red[4];
    if ((tid & 63) == 0) red[tid >> 6] = ss;
    __syncthreads();
    ss = red[0] + red[1] + red[2] + red[3];
    const float inv = rsqrtf(ss * (1.0f / DDIM) + EPS);
    const float4 sc = reinterpret_cast<const float4*>(scale)[tid];
    f16x4_t o;
    o.x = (f16_t)(v.x * inv * sc.x);
    o.y = (f16_t)(v.y * inv * sc.y);
    o.z = (f16_t)(v.z * inv * sc.z);
    o.w = (f16_t)(v.w * inv * sc.w);
    reinterpret_cast<f16x4_t*>(xn + (size_t)row * DDIM)[tid] = o;
}

// ---------------------------------------------------------------------------
// Merged weight prep (one launch, grid (64,32,4)):
//  z=0: (wq,wg) pair-interleaved -> WT slots 0..1
//  z=1: (wk,wv) pair-interleaved -> WT slots 2..3
//  z=2: wo plain transpose       -> WT slot 6
//  z=3: wa half-interleaved      -> WT slots 4..5
// z<3 use only blockIdx.x<32 (idle blocks exit before any barrier).
// ---------------------------------------------------------------------------
__global__ __launch_bounds__(256) void wprep_kernel(
    const float* __restrict__ wq, const float* __restrict__ wk,
    const float* __restrict__ wv, const float* __restrict__ wa,
    const float* __restrict__ wg, const float* __restrict__ wo,
    f16_t* __restrict__ WT)
{
    const size_t WSZ = (size_t)DDIM * DDIM;
    const int z = blockIdx.z;
    __shared__ float t0[32][33];
    __shared__ float t1[32][33];
    const int kb = blockIdx.y * 32;
    const int r  = threadIdx.x >> 3;
    const int c0 = (threadIdx.x & 7) << 2;

    if (z == 3) {
        // wa: W[K][2048] -> WT[n][K], row n <- col (n>>1) + (n&1)*1024
        const int K = DDIM, N = 2 * DDIM;
        const int nb = blockIdx.x * 32;
        const int base = (c0 < 16) ? ((nb >> 1) + c0) : (DDIM + (nb >> 1) + c0 - 16);
        const float4 v = *reinterpret_cast<const float4*>(&wa[(size_t)(kb + r) * N + base]);
        t0[r][c0 + 0] = v.x; t0[r][c0 + 1] = v.y; t0[r][c0 + 2] = v.z; t0[r][c0 + 3] = v.w;
        __syncthreads();
        const int ctile = (r >> 1) + (r & 1) * 16;
        f16x4_t o;
        o.x = (f16_t)t0[c0 + 0][ctile];
        o.y = (f16_t)t0[c0 + 1][ctile];
        o.z = (f16_t)t0[c0 + 2][ctile];
        o.w = (f16_t)t0[c0 + 3][ctile];
        *reinterpret_cast<f16x4_t*>(&WT[4 * WSZ + (size_t)(nb + r) * K + kb + c0]) = o;
        return;
    }
    if (blockIdx.x >= 32) return;
    const int nb = blockIdx.x * 32;
    const int K = DDIM, N = DDIM;
    if (z == 2) {
        // wo plain transpose -> slot 6
        const float4 v = *reinterpret_cast<const float4*>(&wo[(size_t)(kb + r) * N + nb + c0]);
        t0[r][c0 + 0] = v.x; t0[r][c0 + 1] = v.y; t0[r][c0 + 2] = v.z; t0[r][c0 + 3] = v.w;
        __syncthreads();
        f16x4_t o;
        o.x = (f16_t)t0[c0 + 0][r];
        o.y = (f16_t)t0[c0 + 1][r];
        o.z = (f16_t)t0[c0 + 2][r];
        o.w = (f16_t)t0[c0 + 3][r];
        *reinterpret_cast<f16x4_t*>(&WT[6 * WSZ + (size_t)(nb + r) * K + kb + c0]) = o;
        return;
    }
    // z=0/1: pair-interleave (W0,W1): WT[2n][k]=W0[k][n], WT[2n+1][k]=W1[k][n]
    const float* W0 = (z == 0) ? wq : wk;
    const float* W1 = (z == 0) ? wg : wv;
    f16_t* dst = WT + (size_t)(z * 2) * WSZ;
    const float4 v0 = *reinterpret_cast<const float4*>(&W0[(size_t)(kb + r) * N + nb + c0]);
    const float4 v1 = *reinterpret_cast<const float4*>(&W1[(size_t)(kb + r) * N + nb + c0]);
    t0[r][c0 + 0] = v0.x; t0[r][c0 + 1] = v0.y; t0[r][c0 + 2] = v0.z; t0[r][c0 + 3] = v0.w;
    t1[r][c0 + 0] = v1.x; t1[r][c0 + 1] = v1.y; t1[r][c0 + 2] = v1.z; t1[r][c0 + 3] = v1.w;
    __syncthreads();
    const int rr  = threadIdx.x >> 2;        // output row in block: 0..63
    const int cc0 = (threadIdx.x & 3) << 3;  // 0,8,16,24
    const int n   = rr >> 1;                 // source col within tile
    f16x8_t o;
    if (rr & 1) {
        #pragma unroll
        for (int e = 0; e < 8; ++e) o[e] = (f16_t)t1[cc0 + e][n];
    } else {
        #pragma unroll
        for (int e = 0; e < 8; ++e) o[e] = (f16_t)t0[cc0 + e][n];
    }
    *reinterpret_cast<f16x8_t*>(&dst[(size_t)(2 * nb + rr) * K + kb + cc0]) = o;
}

// ---------------------------------------------------------------------------
// fp16 MFMA GEMM (m97 pattern, R4-proven core): C[M,N] = A[M,K] @ BT[N,K]^T
// 128x128 tile, BK=32, 256 threads = 4 waves, each wave 64x64 (4x4 MFMA tiles).
//
// Block mapping: two-level XCD swizzle with 8x8 CO-RESIDENCY PATCHES.
//   R7's linear per-XCD order put ~64 co-resident blocks on 1 bm-row x 48 bn
//   -> B working set 12.6 MB >> 4 MB L2 -> FETCH 708 MB (weights re-streamed
//   per bm-panel). Fix: XCD = lid&7 owns a contiguous bm-stripe (gy/8 rows);
//   within the XCD, blocks walk 64-block patches of 8 bm x 8 bn = 2MB A +
//   2MB B = exactly L2. bn-patch-fastest order keeps the A-stripe resident.
//   Requires gy%8==0, gx%8==0 (holds: gy=128, gx in {48,8}).
//  - quad-XOR LDS swizzle (R4: bank conflicts 12.6M -> 0)
// MODE 0: C(f32) = A@B  (final GEMM)
// MODE 7: merged projections, N=6144 over WT slots qg|kv|a:
//   bn<2048:       qsg = q*silu(g) -> Cv   (pairs; LDS-staged full-line write)
//   2048<=bn<4096: kv  = k*v       -> Cv2  (pairs; LDS-staged full-line write)
//   bn>=4096:      a-polar fused   -> Cv3  (direct; row stride 2048)
// Pair regions: adjacent lanes hold (X=even col, Y=odd col); even lane keeps
// the product. LDS staging then 128B line-aligned row copies eliminates
// partial-line write-allocate fetches (R7-verified: WRITE 150 MB ~= ideal).
// ---------------------------------------------------------------------------
template <int MODE>
__global__ __launch_bounds__(256, 2) void mfma_gemm_kernel(
    const f16_t* __restrict__ A, const f16_t* __restrict__ BT,
    void* __restrict__ Cv, void* __restrict__ Cv2, void* __restrict__ Cv3,
    int M, int N, int K)
{
    // smem: K-loop uses [0..4095]=As, [4096..8191]=Bs (each 128x32 f16).
    // MODE-7 pair epilogue reuses it as [128][68] f16.
    __shared__ __align__(16) f16_t smem[128 * 68];
    f16_t* As = smem;
    f16_t* Bs = smem + 128 * 32;

    const int tid  = threadIdx.x;
    const int wave = tid >> 6;
    const int lane = tid & 63;

    // ---- two-level XCD patch swizzle -------------------------------------
    const int gx    = gridDim.x;
    const int gy    = gridDim.y;
    const int lid   = blockIdx.y * gx + blockIdx.x;
    const int xcd   = lid & 7;
    const int local = lid >> 3;
    const int rows  = gy >> 3;          // bm blocks per XCD stripe
    const int npn   = gx >> 3;          // bn patches
    const int patch = local >> 6;
    const int wi    = local & 63;
    const int pnp   = patch % npn;      // bn patch (fastest -> A-stripe reuse)
    const int pmp   = patch / npn;      // bm patch within stripe
    const int bm = (xcd * rows + pmp * 8 + (wi >> 3)) * 128;
    const int bn = (pnp * 8 + (wi & 7)) * 128;

    const int wm = (wave & 1) * 64;
    const int wn = (wave >> 1) * 64;

    // ---- staging: quad-contiguous, within-quad chunk XOR -----------------
    const int sr = tid >> 2;
    const int sc = (((tid & 3) ^ ((tid >> 3) & 3)) << 3);   // swizzled chunk
    const f16_t* Ag = A  + (size_t)(bm + sr) * K + sc;
    const f16_t* Bg = BT + (size_t)(bn + sr) * K + sc;
    f16_t* Al0 = As + tid * 8;
    f16_t* Al1 = As + 64 * 32 + tid * 8;
    f16_t* Bl0 = Bs + tid * 8;
    f16_t* Bl1 = Bs + 64 * 32 + tid * 8;
    const size_t rowskip = (size_t)64 * K;

    f32x4_t acc[4][4] = {};

    // ---- frag read: same XOR key ((row>>1)&3 == (lane>>1)&3) -------------
    const int fm = lane & 15;
    const int kh = (((lane >> 4) ^ ((lane >> 1) & 3)) << 3);

    for (int kt = 0; kt < K; kt += 32) {
        gload16(Ag + kt, Al0);
        gload16(Ag + rowskip + kt, Al1);
        gload16(Bg + kt, Bl0);
        gload16(Bg + rowskip + kt, Bl1);
        __syncthreads();

        f16x8_t af[4], bfr[4];
        #pragma unroll
        for (int i = 0; i < 4; ++i)
            af[i] = *reinterpret_cast<const f16x8_t*>(&As[(wm + i * 16 + fm) * 32 + kh]);
        #pragma unroll
        for (int j = 0; j < 4; ++j)
            bfr[j] = *reinterpret_cast<const f16x8_t*>(&Bs[(wn + j * 16 + fm) * 32 + kh]);
        #pragma unroll
        for (int i = 0; i < 4; ++i)
            #pragma unroll
            for (int j = 0; j < 4; ++j)
                acc[i][j] = __builtin_amdgcn_mfma_f32_16x16x32_f16(
                    af[i], bfr[j], acc[i][j], 0, 0, 0);
        __syncthreads();
    }

    // epilogue: D row=(lane>>4)*4+reg, col=lane&15  (m89/m91-verified)
    const int erow = (lane >> 4) << 2;
    const int ecol = lane & 15;

    if (MODE == 7 && bn < 4096) {
        // ---- pair-product regions: stage to LDS, full-line copy out ------
        const bool isQ = (bn < 2048);
        #pragma unroll
        for (int i = 0; i < 4; ++i) {
            #pragma unroll
            for (int j = 0; j < 4; ++j) {
                #pragma unroll
                for (int rg = 0; rg < 4; ++rg) {
                    const float val = acc[i][j][rg];
                    const float par = __shfl_xor(val, 1, 64);
                    if (!(lane & 1)) {
                        const float X = val, Y = par;
                        const float outv = isQ ? X * (Y / (1.0f + __expf(-Y)))
                                               : X * Y;
                        smem[(wm + i * 16 + erow + rg) * 68
                             + (wn >> 1) + j * 8 + (ecol >> 1)] = (f16_t)outv;
                    }
                }
            }
        }
        __syncthreads();
        f16_t* dstb = isQ ? (f16_t*)Cv : (f16_t*)Cv2;
        const int prow = tid >> 1;
        const int phal = (tid & 1) * 32;
        const f16_t* src = smem + prow * 68 + phal;
        f16_t* d = dstb + (size_t)(bm + prow) * DDIM + ((bn & 2047) >> 1) + phal;
        #pragma unroll
        for (int q = 0; q < 4; ++q)
            *reinterpret_cast<f16x8_t*>(d + q * 8) =
                *reinterpret_cast<const f16x8_t*>(src + q * 8);
        return;
    }

    #pragma unroll
    for (int i = 0; i < 4; ++i) {
        #pragma unroll
        for (int j = 0; j < 4; ++j) {
            const int row0 = bm + wm + i * 16 + erow;
            const int col  = bn + wn + j * 16 + ecol;
            #pragma unroll
            for (int rg = 0; rg < 4; ++rg) {
                const float val = acc[i][j][rg];
                if (MODE == 0) {
                    ((float*)Cv)[(size_t)(row0 + rg) * N + col] = val;
                } else {  // MODE 7, a-polar region (bn >= 4096)
                    const float par = __shfl_xor(val, 1, 64);
                    const float re = (lane & 1) ? par : val;
                    const float im = (lane & 1) ? val : par;
                    const float r = sqrtf(re * re + im * im);
                    float outv;
                    if (r > 0.0f) {
                        const float sg = 1.0f / (1.0f + __expf(-r));
                        outv = val * (sg / r);
                    } else {
                        outv = (lane & 1) ? 0.0f : 0.5f;
                    }
                    ((f16_t*)Cv3)[(size_t)(row0 + rg) * (2 * DDIM)
                                  + (col - 4096)] = (f16_t)outv;
                }
            }
        }
    }
}

// ---------------------------------------------------------------------------
// Scan phase 1 (x2 channels/thread): per-(b,chunk,d-pair) local scan;
// emit (A_prod, H_local) float4 per channel. a layout: [m][d] f16x2 (re,im).
// ---------------------------------------------------------------------------
__global__ __launch_bounds__(256) void scan1_kernel(
    const f16x2_t* __restrict__ a2, const f16_t* __restrict__ kvb,
    float4* __restrict__ state)
{
    const int t = blockIdx.x * 256 + threadIdx.x;   // B*NCHUNK*512
    const int d2 = (t & 511) << 1;
    const int c = (t >> 9) & (NCHUNK - 1);
    const int b = t >> 15;
    size_t base  = ((size_t)(b * SDIM + c * LCHUNK)) * DDIM + d2;
    float Ar0 = 1.0f, Ai0 = 0.0f, Hr0 = 0.0f, Hi0 = 0.0f;
    float Ar1 = 1.0f, Ai1 = 0.0f, Hr1 = 0.0f, Hi1 = 0.0f;
    for (int s = 0; s < LCHUNK; ++s) {
        const f16x4_t av = *reinterpret_cast<const f16x4_t*>(&a2[base]);   // 2 ch
        const f16x2_t kv2 = *reinterpret_cast<const f16x2_t*>(&kvb[base]);
        {
            const float ar = (float)av.x, ai = (float)av.y, kv = (float)kv2.x;
            const float hr = ar * Hr0 - ai * Hi0 + kv;
            const float hi = ar * Hi0 + ai * Hr0;
            Hr0 = hr; Hi0 = hi;
            const float nr = ar * Ar0 - ai * Ai0;
            const float ni = ar * Ai0 + ai * Ar0;
            Ar0 = nr; Ai0 = ni;
        }
        {
            const float ar = (float)av.z, ai = (float)av.w, kv = (float)kv2.y;
            const float hr = ar * Hr1 - ai * Hi1 + kv;
            const float hi = ar * Hi1 + ai * Hr1;
            Hr1 = hr; Hi1 = hi;
            const float nr = ar * Ar1 - ai * Ai1;
            const float ni = ar * Ai1 + ai * Ar1;
            Ar1 = nr; Ai1 = ni;
        }
        base += DDIM;
    }
    const size_t st = ((size_t)(b * NCHUNK + c)) * DDIM + d2;
    state[st]     = make_float4(Ar0, Ai0, Hr0, Hi0);
    state[st + 1] = make_float4(Ar1, Ai1, Hr1, Hi1);
}

// ---------------------------------------------------------------------------
// Scan phase 2: wave-parallel chunk combine. Lane c holds chunk c's state;
// 6-step Hillis-Steele inclusive scan of (A,H)∘, then exclusive-shift -> carry.
// ---------------------------------------------------------------------------
__global__ __launch_bounds__(256) void scan2_kernel(
    const float4* __restrict__ state, float2* __restrict__ carry)
{
    const int t = blockIdx.x * 256 + threadIdx.x;   // B*D*64 threads
    const int c = t & 63;            // chunk index = lane
    const int ch = t >> 6;           // channel: b*1024+d
    const int d = ch & 1023;
    const int b = ch >> 10;
    const size_t idx = ((size_t)(b * NCHUNK + c)) * DDIM + d;
    const float4 st = state[idx];
    float Ar = st.x, Ai = st.y, Hr = st.z, Hi = st.w;
    #pragma unroll
    for (int off = 1; off < 64; off <<= 1) {
        const float pAr = __shfl_up(Ar, off, 64);
        const float pAi = __shfl_up(Ai, off, 64);
        const float pHr = __shfl_up(Hr, off, 64);
        const float pHi = __shfl_up(Hi, off, 64);
        if (c >= off) {
            // compose(earlier=(pA,pH), current=(A,H)): A·pA, A·pH + H
            const float nHr = Ar * pHr - Ai * pHi + Hr;
            const float nHi = Ar * pHi + Ai * pHr + Hi;
            const float nAr = Ar * pAr - Ai * pAi;
            const float nAi = Ar * pAi + Ai * pAr;
            Ar = nAr; Ai = nAi; Hr = nHr; Hi = nHi;
        }
    }
    // exclusive prefix: carry into chunk c = inclusive H at chunk c-1
    const float eHr = __shfl_up(Hr, 1, 64);
    const float eHi = __shfl_up(Hi, 1, 64);
    carry[idx] = make_float2(c == 0 ? 0.0f : eHr, c == 0 ? 0.0f : eHi);
}

// ---------------------------------------------------------------------------
// Scan phase 3 (x2 channels/thread): re-scan with carry;
// y(f16) = qsg * Re(h), written IN-PLACE over kv.  (qsg = q*silu(g), fused
// in the merged GEMM epilogue.)
// ---------------------------------------------------------------------------
__global__ __launch_bounds__(256) void scan3_kernel(
    const f16x2_t* __restrict__ a2, f16_t* __restrict__ kvb,
    const f16_t* __restrict__ qsgb, const float2* __restrict__ carry)
{
    const int t = blockIdx.x * 256 + threadIdx.x;   // B*NCHUNK*512
    const int d2 = (t & 511) << 1;
    const int c = (t >> 9) & (NCHUNK - 1);
    const int b = t >> 15;
    size_t base  = ((size_t)(b * SDIM + c * LCHUNK)) * DDIM + d2;
    const size_t st = ((size_t)(b * NCHUNK + c)) * DDIM + d2;
    const float2 h0a = carry[st];
    const float2 h0b = carry[st + 1];
    float Hr0 = h0a.x, Hi0 = h0a.y;
    float Hr1 = h0b.x, Hi1 = h0b.y;
    for (int s = 0; s < LCHUNK; ++s) {
        const f16x4_t av = *reinterpret_cast<const f16x4_t*>(&a2[base]);
        const f16x2_t kv2 = *reinterpret_cast<const f16x2_t*>(&kvb[base]);
        const f16x2_t qs2 = *reinterpret_cast<const f16x2_t*>(&qsgb[base]);
        f16x2_t y;
        {
            const float ar = (float)av.x, ai = (float)av.y, kv = (float)kv2.x;
            const float hr = ar * Hr0 - ai * Hi0 + kv;
            const float hi = ar * Hi0 + ai * Hr0;
            Hr0 = hr; Hi0 = hi;
            y.x = (f16_t)((float)qs2.x * hr);
        }
        {
            const float ar = (float)av.z, ai = (float)av.w, kv = (float)kv2.y;
            const float hr = ar * Hr1 - ai * Hi1 + kv;
            const float hi = ar * Hi1 + ai * Hr1;
            Hr1 = hr; Hi1 = hi;
            y.y = (f16_t)((float)qs2.y * hr);
        }
        *reinterpret_cast<f16x2_t*>(&kvb[base]) = y;
        base += DDIM;
    }
}

// ---------------------------------------------------------------------------
// kernel_launch
//
// Workspace layout (149 MB):
//   xn:  [SZ f16]   33.5MB — A operand; scan `state` (4MB) overlaps after death
//   kv:  [SZ f16]   33.5MB — kv=k*v (fused GEMM), then y (in-place in scan3)
//   a:   [SZ f16x2] 67MB   — interleaved (re,im) channel pairs
//   WT:  [7*WSZ f16] 14MB  — slots: 0..1=qg 2..3=kv 4..5=a (all interleaved),
//        6=o; `carry` (2MB) overlaps dead slot 0 after the projection GEMM
// qsg (f16) lives in the first half of d_out until the final GEMM overwrites it.
// Launches: rmsnorm, wprep, proj-GEMM(N=6144), scan1, scan2, scan3, final GEMM.
// ---------------------------------------------------------------------------
extern "C" void kernel_launch(void* const* d_in, const int* in_sizes, int n_in,
                              void* d_out, int out_size, void* d_ws, size_t ws_size,
                              hipStream_t stream)
{
    const float* x        = (const float*)d_in[0];
    const float* wq       = (const float*)d_in[1];
    const float* wk       = (const float*)d_in[2];
    const float* wv       = (const float*)d_in[3];
    const float* wa       = (const float*)d_in[4];
    const float* wg       = (const float*)d_in[5];
    const float* wo       = (const float*)d_in[6];
    const float* rms_scale= (const float*)d_in[7];
    float* out = (float*)d_out;

    const size_t SZ = (size_t)MROWS * DDIM;   // 16,777,216 elements
    const size_t WSZ = (size_t)DDIM * DDIM;   // 1,048,576
    char* ws = (char*)d_ws;
    f16_t*   xn   = (f16_t*)ws;                        // SZ f16
    f16_t*   kv   = (f16_t*)(ws + SZ * 2);             // SZ f16
    f16x2_t* abuf = (f16x2_t*)(ws + SZ * 4);           // SZ f16x2
    f16_t*   WT   = (f16_t*)(ws + SZ * 8);             // 7*WSZ f16
    f16_t* WTo  = WT + 6 * WSZ;      // slot 6
    float4* state = (float4*)xn;     // overlaps dead xn (4MB)
    float2* carry = (float2*)WT;     // overlaps dead WT slot 0 (2MB)

    f16_t* qsgb = (f16_t*)d_out;     // qsg f16 in first half of d_out

    const size_t needed = SZ * 8 + 7 * WSZ * 2;
    if (ws_size < needed) {
        const float marker = (float)(ws_size >> 20);
        fill_kernel<<<(out_size + 255) / 256, 256, 0, stream>>>(out, out_size, marker);
        return;
    }

    // 1. RMSNorm -> f16 xn
    rmsnorm_kernel<<<MROWS, 256, 0, stream>>>(x, rms_scale, xn);

    // 2. Weight prep (single launch)
    dim3 wgrid(64, 32, 4);
    wprep_kernel<<<wgrid, 256, 0, stream>>>(wq, wk, wv, wa, wg, wo, WT);

    // 3. Merged projection GEMM: N=6144 over WT slots qg|kv|a
    //    -> qsg (d_out), kv=k*v (ws), a-polar (abuf)
    dim3 blk(256);
    dim3 gp(6 * DDIM / 128, MROWS / 128);     // (48,128)
    mfma_gemm_kernel<7><<<gp, blk, 0, stream>>>(xn, WT, qsgb, kv, abuf,
                                                MROWS, 6 * DDIM, DDIM);

    // 4. chunked complex scan (x2-channel vectorized phases 1 & 3)
    const int nscan2 = BDIM * NCHUNK * 512;   // 131072 threads
    const int nscan  = BDIM * NCHUNK * DDIM;  // 262144 threads (phase 2)
    scan1_kernel<<<nscan2 / 256, 256, 0, stream>>>(abuf, kv, state);
    scan2_kernel<<<nscan / 256, 256, 0, stream>>>(state, carry);
    scan3_kernel<<<nscan2 / 256, 256, 0, stream>>>(abuf, kv, qsgb, carry);

    // 5. out = y @ wo   (y lives in kv buffer)
    dim3 g1(DDIM / 128, MROWS / 128);         // (8,128)
    mfma_gemm_kernel<0><<<g1, blk, 0, stream>>>(kv, WTo, out, nullptr, nullptr,
                                                MROWS, DDIM, DDIM);
}

// Round 9
// 416.291 us; speedup vs baseline: 1.0274x; 1.0076x over previous
//
#include <hip/hip_runtime.h>
#include <hip/hip_bf16.h>
#include <math.h>

// Problem constants (B,S,D) = (4,4096,1024)
#define BDIM 4
#define SDIM 4096
#define DDIM 1024
#define MROWS (BDIM*SDIM)      // 16384
#define EPS 1e-6f
#define NCHUNK 64              // chunks along S
#define LCHUNK 64              // chunk length (NCHUNK*LCHUNK == SDIM)

typedef _Float16 f16_t;
typedef _Float16 f16x2_t __attribute__((ext_vector_type(2)));
typedef _Float16 f16x4_t __attribute__((ext_vector_type(4)));
typedef _Float16 f16x8_t __attribute__((ext_vector_type(8)));     // MFMA A/B frag (4 VGPRs)
typedef float    f32x4_t __attribute__((ext_vector_type(4)));     // MFMA C/D frag

// async global->LDS, 16B per lane (dest = wave-uniform base + lane*16)
__device__ __forceinline__ void gload16(const void* g, void* l) {
    __builtin_amdgcn_global_load_lds(
        (const __attribute__((address_space(1))) unsigned int*)g,
        (__attribute__((address_space(3))) unsigned int*)l, 16, 0, 0);
}

// ---------------------------------------------------------------------------
// Guard-fail fill (encodes ws_size MB as output on too-small workspace)
// ---------------------------------------------------------------------------
__global__ __launch_bounds__(256) void fill_kernel(float* __restrict__ out,
                                                   int n, float val)
{
    const int i = blockIdx.x * 256 + threadIdx.x;
    if (i < n) out[i] = val;
}

// ---------------------------------------------------------------------------
// RMSNorm: one block per row of D=1024; outputs fp16 xn.
// ---------------------------------------------------------------------------
__global__ __launch_bounds__(256) void rmsnorm_kernel(
    const float* __restrict__ x, const float* __restrict__ scale,
    f16_t* __restrict__ xn)
{
    const int row = blockIdx.x;
    const int tid = threadIdx.x;
    const float4 v = reinterpret_cast<const float4*>(x + (size_t)row * DDIM)[tid];
    float ss = v.x*v.x + v.y*v.y + v.z*v.z + v.w*v.w;
    #pragma unroll
    for (int off = 32; off > 0; off >>= 1)
        ss += __shfl_down(ss, off, 64);
    __shared__ float red[4];
    if ((tid & 63) == 0) red[tid >> 6] = ss;
    __syncthreads();
    ss = red[0] + red[1] + red[2] + red[3];
    const float inv = rsqrtf(ss * (1.0f / DDIM) + EPS);
    const float4 sc = reinterpret_cast<const float4*>(scale)[tid];
    f16x4_t o;
    o.x = (f16_t)(v.x * inv * sc.x);
    o.y = (f16_t)(v.y * inv * sc.y);
    o.z = (f16_t)(v.z * inv * sc.z);
    o.w = (f16_t)(v.w * inv * sc.w);
    reinterpret_cast<f16x4_t*>(xn + (size_t)row * DDIM)[tid] = o;
}

// ---------------------------------------------------------------------------
// Merged weight prep (one launch, grid (64,32,4)):
//  z=0: (wq,wg) pair-interleaved -> WT slots 0..1
//  z=1: (wk,wv) pair-interleaved -> WT slots 2..3
//  z=2: wo plain transpose       -> WT slot 6
//  z=3: wa half-interleaved      -> WT slots 4..5
// z<3 use only blockIdx.x<32 (idle blocks exit before any barrier).
// ---------------------------------------------------------------------------
__global__ __launch_bounds__(256) void wprep_kernel(
    const float* __restrict__ wq, const float* __restrict__ wk,
    const float* __restrict__ wv, const float* __restrict__ wa,
    const float* __restrict__ wg, const float* __restrict__ wo,
    f16_t* __restrict__ WT)
{
    const size_t WSZ = (size_t)DDIM * DDIM;
    const int z = blockIdx.z;
    __shared__ float t0[32][33];
    __shared__ float t1[32][33];
    const int kb = blockIdx.y * 32;
    const int r  = threadIdx.x >> 3;
    const int c0 = (threadIdx.x & 7) << 2;

    if (z == 3) {
        // wa: W[K][2048] -> WT[n][K], row n <- col (n>>1) + (n&1)*1024
        const int K = DDIM, N = 2 * DDIM;
        const int nb = blockIdx.x * 32;
        const int base = (c0 < 16) ? ((nb >> 1) + c0) : (DDIM + (nb >> 1) + c0 - 16);
        const float4 v = *reinterpret_cast<const float4*>(&wa[(size_t)(kb + r) * N + base]);
        t0[r][c0 + 0] = v.x; t0[r][c0 + 1] = v.y; t0[r][c0 + 2] = v.z; t0[r][c0 + 3] = v.w;
        __syncthreads();
        const int ctile = (r >> 1) + (r & 1) * 16;
        f16x4_t o;
        o.x = (f16_t)t0[c0 + 0][ctile];
        o.y = (f16_t)t0[c0 + 1][ctile];
        o.z = (f16_t)t0[c0 + 2][ctile];
        o.w = (f16_t)t0[c0 + 3][ctile];
        *reinterpret_cast<f16x4_t*>(&WT[4 * WSZ + (size_t)(nb + r) * K + kb + c0]) = o;
        return;
    }
    if (blockIdx.x >= 32) return;
    const int nb = blockIdx.x * 32;
    const int K = DDIM, N = DDIM;
    if (z == 2) {
        // wo plain transpose -> slot 6
        const float4 v = *reinterpret_cast<const float4*>(&wo[(size_t)(kb + r) * N + nb + c0]);
        t0[r][c0 + 0] = v.x; t0[r][c0 + 1] = v.y; t0[r][c0 + 2] = v.z; t0[r][c0 + 3] = v.w;
        __syncthreads();
        f16x4_t o;
        o.x = (f16_t)t0[c0 + 0][r];
        o.y = (f16_t)t0[c0 + 1][r];
        o.z = (f16_t)t0[c0 + 2][r];
        o.w = (f16_t)t0[c0 + 3][r];
        *reinterpret_cast<f16x4_t*>(&WT[6 * WSZ + (size_t)(nb + r) * K + kb + c0]) = o;
        return;
    }
    // z=0/1: pair-interleave (W0,W1): WT[2n][k]=W0[k][n], WT[2n+1][k]=W1[k][n]
    const float* W0 = (z == 0) ? wq : wk;
    const float* W1 = (z == 0) ? wg : wv;
    f16_t* dst = WT + (size_t)(z * 2) * WSZ;
    const float4 v0 = *reinterpret_cast<const float4*>(&W0[(size_t)(kb + r) * N + nb + c0]);
    const float4 v1 = *reinterpret_cast<const float4*>(&W1[(size_t)(kb + r) * N + nb + c0]);
    t0[r][c0 + 0] = v0.x; t0[r][c0 + 1] = v0.y; t0[r][c0 + 2] = v0.z; t0[r][c0 + 3] = v0.w;
    t1[r][c0 + 0] = v1.x; t1[r][c0 + 1] = v1.y; t1[r][c0 + 2] = v1.z; t1[r][c0 + 3] = v1.w;
    __syncthreads();
    const int rr  = threadIdx.x >> 2;        // output row in block: 0..63
    const int cc0 = (threadIdx.x & 3) << 3;  // 0,8,16,24
    const int n   = rr >> 1;                 // source col within tile
    f16x8_t o;
    if (rr & 1) {
        #pragma unroll
        for (int e = 0; e < 8; ++e) o[e] = (f16_t)t1[cc0 + e][n];
    } else {
        #pragma unroll
        for (int e = 0; e < 8; ++e) o[e] = (f16_t)t0[cc0 + e][n];
    }
    *reinterpret_cast<f16x8_t*>(&dst[(size_t)(2 * nb + rr) * K + kb + cc0]) = o;
}

// ---------------------------------------------------------------------------
// fp16 MFMA GEMM (m97 pattern, R4-proven core): C[M,N] = A[M,K] @ BT[N,K]^T
// 128x128 tile, BK=32, 256 threads = 4 waves, each wave 64x64 (4x4 MFMA tiles).
//
// Block mapping: two-level XCD swizzle with 8x8 CO-RESIDENCY PATCHES
// (R8-verified: FETCH 708 -> 164 MB on the merged launch). XCD = lid&7 owns
// a contiguous bm-stripe; within it, 64-block patches of 8 bm x 8 bn = 4 MB
// = L2. Requires gy%8==0, gx%8==0 (gy=128; gx in {32,16,8}).
//  - quad-XOR LDS swizzle (R4: bank conflicts 12.6M -> 0)
//
// R9: UN-MERGED projections (pre-commit from R8: merged per-round cost
// 25.2 us vs split 22.5-23.3 us; with FETCH fixed by the patch swizzle the
// merge overhead dominates -> split wins ~30 us).
// MODE 0: C(f32) = A@B  (final GEMM)
// MODE 4: a-polar fused -> f16 (N=2048): val*sigmoid(|a|)/|a|, direct
//         writes (wave covers full 128B lines per (i,rg)).
// MODE 6: pair-product (N=4096): bn<2048: qsg = q*silu(g) -> Cv;
//         else kv = k*v -> Cv2. Adjacent lanes hold (X,Y); LDS-staged
//         full-line writes (R7/R8-verified: WRITE ~= ideal).
// ---------------------------------------------------------------------------
template <int MODE>
__global__ __launch_bounds__(256, 2) void mfma_gemm_kernel(
    const f16_t* __restrict__ A, const f16_t* __restrict__ BT,
    void* __restrict__ Cv, void* __restrict__ Cv2, void* __restrict__ Cv3,
    int M, int N, int K)
{
    // smem: K-loop uses [0..4095]=As, [4096..8191]=Bs (each 128x32 f16).
    // MODE-6 pair epilogue reuses it as [128][68] f16.
    __shared__ __align__(16) f16_t smem[128 * 68];
    f16_t* As = smem;
    f16_t* Bs = smem + 128 * 32;

    const int tid  = threadIdx.x;
    const int wave = tid >> 6;
    const int lane = tid & 63;

    // ---- two-level XCD patch swizzle -------------------------------------
    const int gx    = gridDim.x;
    const int gy    = gridDim.y;
    const int lid   = blockIdx.y * gx + blockIdx.x;
    const int xcd   = lid & 7;
    const int local = lid >> 3;
    const int rows  = gy >> 3;          // bm blocks per XCD stripe
    const int npn   = gx >> 3;          // bn patches
    const int patch = local >> 6;
    const int wi    = local & 63;
    const int pnp   = patch % npn;      // bn patch (fastest -> A-stripe reuse)
    const int pmp   = patch / npn;      // bm patch within stripe
    const int bm = (xcd * rows + pmp * 8 + (wi >> 3)) * 128;
    const int bn = (pnp * 8 + (wi & 7)) * 128;

    const int wm = (wave & 1) * 64;
    const int wn = (wave >> 1) * 64;

    // ---- staging: quad-contiguous, within-quad chunk XOR -----------------
    const int sr = tid >> 2;
    const int sc = (((tid & 3) ^ ((tid >> 3) & 3)) << 3);   // swizzled chunk
    const f16_t* Ag = A  + (size_t)(bm + sr) * K + sc;
    const f16_t* Bg = BT + (size_t)(bn + sr) * K + sc;
    f16_t* Al0 = As + tid * 8;
    f16_t* Al1 = As + 64 * 32 + tid * 8;
    f16_t* Bl0 = Bs + tid * 8;
    f16_t* Bl1 = Bs + 64 * 32 + tid * 8;
    const size_t rowskip = (size_t)64 * K;

    f32x4_t acc[4][4] = {};

    // ---- frag read: same XOR key ((row>>1)&3 == (lane>>1)&3) -------------
    const int fm = lane & 15;
    const int kh = (((lane >> 4) ^ ((lane >> 1) & 3)) << 3);

    for (int kt = 0; kt < K; kt += 32) {
        gload16(Ag + kt, Al0);
        gload16(Ag + rowskip + kt, Al1);
        gload16(Bg + kt, Bl0);
        gload16(Bg + rowskip + kt, Bl1);
        __syncthreads();

        f16x8_t af[4], bfr[4];
        #pragma unroll
        for (int i = 0; i < 4; ++i)
            af[i] = *reinterpret_cast<const f16x8_t*>(&As[(wm + i * 16 + fm) * 32 + kh]);
        #pragma unroll
        for (int j = 0; j < 4; ++j)
            bfr[j] = *reinterpret_cast<const f16x8_t*>(&Bs[(wn + j * 16 + fm) * 32 + kh]);
        #pragma unroll
        for (int i = 0; i < 4; ++i)
            #pragma unroll
            for (int j = 0; j < 4; ++j)
                acc[i][j] = __builtin_amdgcn_mfma_f32_16x16x32_f16(
                    af[i], bfr[j], acc[i][j], 0, 0, 0);
        __syncthreads();
    }

    // epilogue: D row=(lane>>4)*4+reg, col=lane&15  (m89/m91-verified)
    const int erow = (lane >> 4) << 2;
    const int ecol = lane & 15;

    if (MODE == 6) {
        // ---- pair-product: stage to LDS, full-line copy out --------------
        const bool isQ = (bn < 2048);
        #pragma unroll
        for (int i = 0; i < 4; ++i) {
            #pragma unroll
            for (int j = 0; j < 4; ++j) {
                #pragma unroll
                for (int rg = 0; rg < 4; ++rg) {
                    const float val = acc[i][j][rg];
                    const float par = __shfl_xor(val, 1, 64);
                    if (!(lane & 1)) {
                        const float X = val, Y = par;
                        const float outv = isQ ? X * (Y / (1.0f + __expf(-Y)))
                                               : X * Y;
                        smem[(wm + i * 16 + erow + rg) * 68
                             + (wn >> 1) + j * 8 + (ecol >> 1)] = (f16_t)outv;
                    }
                }
            }
        }
        __syncthreads();
        f16_t* dstb = isQ ? (f16_t*)Cv : (f16_t*)Cv2;
        const int prow = tid >> 1;
        const int phal = (tid & 1) * 32;
        const f16_t* src = smem + prow * 68 + phal;
        f16_t* d = dstb + (size_t)(bm + prow) * DDIM + ((bn & 2047) >> 1) + phal;
        #pragma unroll
        for (int q = 0; q < 4; ++q)
            *reinterpret_cast<f16x8_t*>(d + q * 8) =
                *reinterpret_cast<const f16x8_t*>(src + q * 8);
        return;
    }

    #pragma unroll
    for (int i = 0; i < 4; ++i) {
        #pragma unroll
        for (int j = 0; j < 4; ++j) {
            const int row0 = bm + wm + i * 16 + erow;
            const int col  = bn + wn + j * 16 + ecol;
            #pragma unroll
            for (int rg = 0; rg < 4; ++rg) {
                const float val = acc[i][j][rg];
                if (MODE == 0) {
                    ((float*)Cv)[(size_t)(row0 + rg) * N + col] = val;
                } else {  // MODE 4: a-polar (N=2048), direct full-line writes
                    const float par = __shfl_xor(val, 1, 64);
                    const float re = (lane & 1) ? par : val;
                    const float im = (lane & 1) ? val : par;
                    const float r = sqrtf(re * re + im * im);
                    float outv;
                    if (r > 0.0f) {
                        const float sg = 1.0f / (1.0f + __expf(-r));
                        outv = val * (sg / r);
                    } else {
                        outv = (lane & 1) ? 0.0f : 0.5f;
                    }
                    ((f16_t*)Cv)[(size_t)(row0 + rg) * N + col] = (f16_t)outv;
                }
            }
        }
    }
}

// ---------------------------------------------------------------------------
// Scan phase 1 (x2 channels/thread): per-(b,chunk,d-pair) local scan;
// emit (A_prod, H_local) float4 per channel. a layout: [m][d] f16x2 (re,im).
// ---------------------------------------------------------------------------
__global__ __launch_bounds__(256) void scan1_kernel(
    const f16x2_t* __restrict__ a2, const f16_t* __restrict__ kvb,
    float4* __restrict__ state)
{
    const int t = blockIdx.x * 256 + threadIdx.x;   // B*NCHUNK*512
    const int d2 = (t & 511) << 1;
    const int c = (t >> 9) & (NCHUNK - 1);
    const int b = t >> 15;
    size_t base  = ((size_t)(b * SDIM + c * LCHUNK)) * DDIM + d2;
    float Ar0 = 1.0f, Ai0 = 0.0f, Hr0 = 0.0f, Hi0 = 0.0f;
    float Ar1 = 1.0f, Ai1 = 0.0f, Hr1 = 0.0f, Hi1 = 0.0f;
    for (int s = 0; s < LCHUNK; ++s) {
        const f16x4_t av = *reinterpret_cast<const f16x4_t*>(&a2[base]);   // 2 ch
        const f16x2_t kv2 = *reinterpret_cast<const f16x2_t*>(&kvb[base]);
        {
            const float ar = (float)av.x, ai = (float)av.y, kv = (float)kv2.x;
            const float hr = ar * Hr0 - ai * Hi0 + kv;
            const float hi = ar * Hi0 + ai * Hr0;
            Hr0 = hr; Hi0 = hi;
            const float nr = ar * Ar0 - ai * Ai0;
            const float ni = ar * Ai0 + ai * Ar0;
            Ar0 = nr; Ai0 = ni;
        }
        {
            const float ar = (float)av.z, ai = (float)av.w, kv = (float)kv2.y;
            const float hr = ar * Hr1 - ai * Hi1 + kv;
            const float hi = ar * Hi1 + ai * Hr1;
            Hr1 = hr; Hi1 = hi;
            const float nr = ar * Ar1 - ai * Ai1;
            const float ni = ar * Ai1 + ai * Ar1;
            Ar1 = nr; Ai1 = ni;
        }
        base += DDIM;
    }
    const size_t st = ((size_t)(b * NCHUNK + c)) * DDIM + d2;
    state[st]     = make_float4(Ar0, Ai0, Hr0, Hi0);
    state[st + 1] = make_float4(Ar1, Ai1, Hr1, Hi1);
}

// ---------------------------------------------------------------------------
// Scan phase 2: wave-parallel chunk combine. Lane c holds chunk c's state;
// 6-step Hillis-Steele inclusive scan of (A,H)∘, then exclusive-shift -> carry.
// ---------------------------------------------------------------------------
__global__ __launch_bounds__(256) void scan2_kernel(
    const float4* __restrict__ state, float2* __restrict__ carry)
{
    const int t = blockIdx.x * 256 + threadIdx.x;   // B*D*64 threads
    const int c = t & 63;            // chunk index = lane
    const int ch = t >> 6;           // channel: b*1024+d
    const int d = ch & 1023;
    const int b = ch >> 10;
    const size_t idx = ((size_t)(b * NCHUNK + c)) * DDIM + d;
    const float4 st = state[idx];
    float Ar = st.x, Ai = st.y, Hr = st.z, Hi = st.w;
    #pragma unroll
    for (int off = 1; off < 64; off <<= 1) {
        const float pAr = __shfl_up(Ar, off, 64);
        const float pAi = __shfl_up(Ai, off, 64);
        const float pHr = __shfl_up(Hr, off, 64);
        const float pHi = __shfl_up(Hi, off, 64);
        if (c >= off) {
            // compose(earlier=(pA,pH), current=(A,H)): A·pA, A·pH + H
            const float nHr = Ar * pHr - Ai * pHi + Hr;
            const float nHi = Ar * pHi + Ai * pHr + Hi;
            const float nAr = Ar * pAr - Ai * pAi;
            const float nAi = Ar * pAi + Ai * pAr;
            Ar = nAr; Ai = nAi; Hr = nHr; Hi = nHi;
        }
    }
    // exclusive prefix: carry into chunk c = inclusive H at chunk c-1
    const float eHr = __shfl_up(Hr, 1, 64);
    const float eHi = __shfl_up(Hi, 1, 64);
    carry[idx] = make_float2(c == 0 ? 0.0f : eHr, c == 0 ? 0.0f : eHi);
}

// ---------------------------------------------------------------------------
// Scan phase 3 (x2 channels/thread): re-scan with carry;
// y(f16) = qsg * Re(h), written IN-PLACE over kv.  (qsg = q*silu(g), fused
// in the mode-6 GEMM epilogue.)
// ---------------------------------------------------------------------------
__global__ __launch_bounds__(256) void scan3_kernel(
    const f16x2_t* __restrict__ a2, f16_t* __restrict__ kvb,
    const f16_t* __restrict__ qsgb, const float2* __restrict__ carry)
{
    const int t = blockIdx.x * 256 + threadIdx.x;   // B*NCHUNK*512
    const int d2 = (t & 511) << 1;
    const int c = (t >> 9) & (NCHUNK - 1);
    const int b = t >> 15;
    size_t base  = ((size_t)(b * SDIM + c * LCHUNK)) * DDIM + d2;
    const size_t st = ((size_t)(b * NCHUNK + c)) * DDIM + d2;
    const float2 h0a = carry[st];
    const float2 h0b = carry[st + 1];
    float Hr0 = h0a.x, Hi0 = h0a.y;
    float Hr1 = h0b.x, Hi1 = h0b.y;
    for (int s = 0; s < LCHUNK; ++s) {
        const f16x4_t av = *reinterpret_cast<const f16x4_t*>(&a2[base]);
        const f16x2_t kv2 = *reinterpret_cast<const f16x2_t*>(&kvb[base]);
        const f16x2_t qs2 = *reinterpret_cast<const f16x2_t*>(&qsgb[base]);
        f16x2_t y;
        {
            const float ar = (float)av.x, ai = (float)av.y, kv = (float)kv2.x;
            const float hr = ar * Hr0 - ai * Hi0 + kv;
            const float hi = ar * Hi0 + ai * Hr0;
            Hr0 = hr; Hi0 = hi;
            y.x = (f16_t)((float)qs2.x * hr);
        }
        {
            const float ar = (float)av.z, ai = (float)av.w, kv = (float)kv2.y;
            const float hr = ar * Hr1 - ai * Hi1 + kv;
            const float hi = ar * Hi1 + ai * Hr1;
            Hr1 = hr; Hi1 = hi;
            y.y = (f16_t)((float)qs2.y * hr);
        }
        *reinterpret_cast<f16x2_t*>(&kvb[base]) = y;
        base += DDIM;
    }
}

// ---------------------------------------------------------------------------
// kernel_launch
//
// Workspace layout (149 MB):
//   xn:  [SZ f16]   33.5MB — A operand; scan `state` (4MB) overlaps after death
//   kv:  [SZ f16]   33.5MB — kv=k*v (fused GEMM), then y (in-place in scan3)
//   a:   [SZ f16x2] 67MB   — interleaved (re,im) channel pairs
//   WT:  [7*WSZ f16] 14MB  — slots: 0..1=qg 2..3=kv 4..5=a (all interleaved),
//        6=o; `carry` (2MB) overlaps dead slot 0 after the projection GEMMs
// qsg (f16) lives in the first half of d_out until the final GEMM overwrites it.
// Launches: rmsnorm, wprep, GEMM6(N=4096), GEMM4(N=2048), scan1/2/3, GEMM0.
// ---------------------------------------------------------------------------
extern "C" void kernel_launch(void* const* d_in, const int* in_sizes, int n_in,
                              void* d_out, int out_size, void* d_ws, size_t ws_size,
                              hipStream_t stream)
{
    const float* x        = (const float*)d_in[0];
    const float* wq       = (const float*)d_in[1];
    const float* wk       = (const float*)d_in[2];
    const float* wv       = (const float*)d_in[3];
    const float* wa       = (const float*)d_in[4];
    const float* wg       = (const float*)d_in[5];
    const float* wo       = (const float*)d_in[6];
    const float* rms_scale= (const float*)d_in[7];
    float* out = (float*)d_out;

    const size_t SZ = (size_t)MROWS * DDIM;   // 16,777,216 elements
    const size_t WSZ = (size_t)DDIM * DDIM;   // 1,048,576
    char* ws = (char*)d_ws;
    f16_t*   xn   = (f16_t*)ws;                        // SZ f16
    f16_t*   kv   = (f16_t*)(ws + SZ * 2);             // SZ f16
    f16x2_t* abuf = (f16x2_t*)(ws + SZ * 4);           // SZ f16x2
    f16_t*   WT   = (f16_t*)(ws + SZ * 8);             // 7*WSZ f16
    f16_t* WTqg = WT;                // slots 0..1 (wq/wg interleaved)
    f16_t* WTkv = WT + 2 * WSZ;      // slots 2..3 (wk/wv interleaved)
    f16_t* WTa  = WT + 4 * WSZ;      // slots 4..5 (wa interleaved halves)
    f16_t* WTo  = WT + 6 * WSZ;      // slot 6
    float4* state = (float4*)xn;     // overlaps dead xn (4MB)
    float2* carry = (float2*)WT;     // overlaps dead WT slot 0 (2MB)

    f16_t* qsgb = (f16_t*)d_out;     // qsg f16 in first half of d_out

    const size_t needed = SZ * 8 + 7 * WSZ * 2;
    if (ws_size < needed) {
        const float marker = (float)(ws_size >> 20);
        fill_kernel<<<(out_size + 255) / 256, 256, 0, stream>>>(out, out_size, marker);
        return;
    }

    // 1. RMSNorm -> f16 xn
    rmsnorm_kernel<<<MROWS, 256, 0, stream>>>(x, rms_scale, xn);

    // 2. Weight prep (single launch)
    dim3 wgrid(64, 32, 4);
    wprep_kernel<<<wgrid, 256, 0, stream>>>(wq, wk, wv, wa, wg, wo, WT);

    // 3. Projections (split; both with patch swizzle)
    dim3 blk(256);
    dim3 g6(4 * DDIM / 128, MROWS / 128);     // (32,128): qg|kv pairs
    dim3 g4(2 * DDIM / 128, MROWS / 128);     // (16,128): a-polar
    mfma_gemm_kernel<6><<<g6, blk, 0, stream>>>(xn, WTqg, qsgb, kv, nullptr,
                                                MROWS, 4 * DDIM, DDIM);
    mfma_gemm_kernel<4><<<g4, blk, 0, stream>>>(xn, WTa, abuf, nullptr, nullptr,
                                                MROWS, 2 * DDIM, DDIM);

    // 4. chunked complex scan (x2-channel vectorized phases 1 & 3)
    const int nscan2 = BDIM * NCHUNK * 512;   // 131072 threads
    const int nscan  = BDIM * NCHUNK * DDIM;  // 262144 threads (phase 2)
    scan1_kernel<<<nscan2 / 256, 256, 0, stream>>>(abuf, kv, state);
    scan2_kernel<<<nscan / 256, 256, 0, stream>>>(state, carry);
    scan3_kernel<<<nscan2 / 256, 256, 0, stream>>>(abuf, kv, qsgb, carry);

    // 5. out = y @ wo   (y lives in kv buffer)
    dim3 g1(DDIM / 128, MROWS / 128);         // (8,128)
    mfma_gemm_kernel<0><<<g1, blk, 0, stream>>>(kv, WTo, out, nullptr, nullptr,
                                                MROWS, DDIM, DDIM);
}

// Round 10
// 391.325 us; speedup vs baseline: 1.0930x; 1.0638x over previous
//
#include <hip/hip_runtime.h>
#include <hip/hip_bf16.h>
#include <math.h>

// Problem constants (B,S,D) = (4,4096,1024)
#define BDIM 4
#define SDIM 4096
#define DDIM 1024
#define MROWS (BDIM*SDIM)      // 16384
#define EPS 1e-6f
#define NCHUNK 64              // chunks along S
#define LCHUNK 64              // chunk length (NCHUNK*LCHUNK == SDIM)

typedef _Float16 f16_t;
typedef _Float16 f16x2_t __attribute__((ext_vector_type(2)));
typedef _Float16 f16x4_t __attribute__((ext_vector_type(4)));
typedef _Float16 f16x8_t __attribute__((ext_vector_type(8)));     // MFMA A/B frag (4 VGPRs)
typedef float    f32x4_t __attribute__((ext_vector_type(4)));     // MFMA C/D frag

// async global->LDS, 16B per lane (dest = wave-uniform base + lane*16)
__device__ __forceinline__ void gload16(const void* g, void* l) {
    __builtin_amdgcn_global_load_lds(
        (const __attribute__((address_space(1))) unsigned int*)g,
        (__attribute__((address_space(3))) unsigned int*)l, 16, 0, 0);
}

// ---------------------------------------------------------------------------
// Guard-fail fill (encodes ws_size MB as output on too-small workspace)
// ---------------------------------------------------------------------------
__global__ __launch_bounds__(256) void fill_kernel(float* __restrict__ out,
                                                   int n, float val)
{
    const int i = blockIdx.x * 256 + threadIdx.x;
    if (i < n) out[i] = val;
}

// ---------------------------------------------------------------------------
// RMSNorm: one block per row of D=1024; outputs fp16 xn.
// ---------------------------------------------------------------------------
__global__ __launch_bounds__(256) void rmsnorm_kernel(
    const float* __restrict__ x, const float* __restrict__ scale,
    f16_t* __restrict__ xn)
{
    const int row = blockIdx.x;
    const int tid = threadIdx.x;
    const float4 v = reinterpret_cast<const float4*>(x + (size_t)row * DDIM)[tid];
    float ss = v.x*v.x + v.y*v.y + v.z*v.z + v.w*v.w;
    #pragma unroll
    for (int off = 32; off > 0; off >>= 1)
        ss += __shfl_down(ss, off, 64);
    __shared__ float red[4];
    if ((tid & 63) == 0) red[tid >> 6] = ss;
    __syncthreads();
    ss = red[0] + red[1] + red[2] + red[3];
    const float inv = rsqrtf(ss * (1.0f / DDIM) + EPS);
    const float4 sc = reinterpret_cast<const float4*>(scale)[tid];
    f16x4_t o;
    o.x = (f16_t)(v.x * inv * sc.x);
    o.y = (f16_t)(v.y * inv * sc.y);
    o.z = (f16_t)(v.z * inv * sc.z);
    o.w = (f16_t)(v.w * inv * sc.w);
    reinterpret_cast<f16x4_t*>(xn + (size_t)row * DDIM)[tid] = o;
}

// ---------------------------------------------------------------------------
// Merged weight prep (one launch, grid (64,32,4)):
//  z=0: (wq,wg) pair-interleaved -> WT slots 0..1
//  z=1: (wk,wv) pair-interleaved -> WT slots 2..3
//  z=2: wo plain transpose       -> WT slot 6
//  z=3: wa half-interleaved      -> WT slots 4..5
// z<3 use only blockIdx.x<32 (idle blocks exit before any barrier).
// ---------------------------------------------------------------------------
__global__ __launch_bounds__(256) void wprep_kernel(
    const float* __restrict__ wq, const float* __restrict__ wk,
    const float* __restrict__ wv, const float* __restrict__ wa,
    const float* __restrict__ wg, const float* __restrict__ wo,
    f16_t* __restrict__ WT)
{
    const size_t WSZ = (size_t)DDIM * DDIM;
    const int z = blockIdx.z;
    __shared__ float t0[32][33];
    __shared__ float t1[32][33];
    const int kb = blockIdx.y * 32;
    const int r  = threadIdx.x >> 3;
    const int c0 = (threadIdx.x & 7) << 2;

    if (z == 3) {
        // wa: W[K][2048] -> WT[n][K], row n <- col (n>>1) + (n&1)*1024
        const int K = DDIM, N = 2 * DDIM;
        const int nb = blockIdx.x * 32;
        const int base = (c0 < 16) ? ((nb >> 1) + c0) : (DDIM + (nb >> 1) + c0 - 16);
        const float4 v = *reinterpret_cast<const float4*>(&wa[(size_t)(kb + r) * N + base]);
        t0[r][c0 + 0] = v.x; t0[r][c0 + 1] = v.y; t0[r][c0 + 2] = v.z; t0[r][c0 + 3] = v.w;
        __syncthreads();
        const int ctile = (r >> 1) + (r & 1) * 16;
        f16x4_t o;
        o.x = (f16_t)t0[c0 + 0][ctile];
        o.y = (f16_t)t0[c0 + 1][ctile];
        o.z = (f16_t)t0[c0 + 2][ctile];
        o.w = (f16_t)t0[c0 + 3][ctile];
        *reinterpret_cast<f16x4_t*>(&WT[4 * WSZ + (size_t)(nb + r) * K + kb + c0]) = o;
        return;
    }
    if (blockIdx.x >= 32) return;
    const int nb = blockIdx.x * 32;
    const int K = DDIM, N = DDIM;
    if (z == 2) {
        // wo plain transpose -> slot 6
        const float4 v = *reinterpret_cast<const float4*>(&wo[(size_t)(kb + r) * N + nb + c0]);
        t0[r][c0 + 0] = v.x; t0[r][c0 + 1] = v.y; t0[r][c0 + 2] = v.z; t0[r][c0 + 3] = v.w;
        __syncthreads();
        f16x4_t o;
        o.x = (f16_t)t0[c0 + 0][r];
        o.y = (f16_t)t0[c0 + 1][r];
        o.z = (f16_t)t0[c0 + 2][r];
        o.w = (f16_t)t0[c0 + 3][r];
        *reinterpret_cast<f16x4_t*>(&WT[6 * WSZ + (size_t)(nb + r) * K + kb + c0]) = o;
        return;
    }
    // z=0/1: pair-interleave (W0,W1): WT[2n][k]=W0[k][n], WT[2n+1][k]=W1[k][n]
    const float* W0 = (z == 0) ? wq : wk;
    const float* W1 = (z == 0) ? wg : wv;
    f16_t* dst = WT + (size_t)(z * 2) * WSZ;
    const float4 v0 = *reinterpret_cast<const float4*>(&W0[(size_t)(kb + r) * N + nb + c0]);
    const float4 v1 = *reinterpret_cast<const float4*>(&W1[(size_t)(kb + r) * N + nb + c0]);
    t0[r][c0 + 0] = v0.x; t0[r][c0 + 1] = v0.y; t0[r][c0 + 2] = v0.z; t0[r][c0 + 3] = v0.w;
    t1[r][c0 + 0] = v1.x; t1[r][c0 + 1] = v1.y; t1[r][c0 + 2] = v1.z; t1[r][c0 + 3] = v1.w;
    __syncthreads();
    const int rr  = threadIdx.x >> 2;        // output row in block: 0..63
    const int cc0 = (threadIdx.x & 3) << 3;  // 0,8,16,24
    const int n   = rr >> 1;                 // source col within tile
    f16x8_t o;
    if (rr & 1) {
        #pragma unroll
        for (int e = 0; e < 8; ++e) o[e] = (f16_t)t1[cc0 + e][n];
    } else {
        #pragma unroll
        for (int e = 0; e < 8; ++e) o[e] = (f16_t)t0[cc0 + e][n];
    }
    *reinterpret_cast<f16x8_t*>(&dst[(size_t)(2 * nb + rr) * K + kb + cc0]) = o;
}

// ---------------------------------------------------------------------------
// fp16 MFMA GEMM: C[M,N] = A[M,K] @ BT[N,K]^T
// 128x128 tile, 256 threads = 4 waves, each wave 64x64 (4x4 MFMA tiles).
//
// R10: BK=64 (was 32). Same 2-barrier m97 structure, HALF the iterations
// (16 vs 32) -> total barrier-drain time (the ~40% neither-pipe residual at
// BK=32: MfmaUtil 33 + VALUBusy 26, HBM 11%) halves. LDS 32 KB (m132's
// regression was BK=128/64KB; this stays clear).
//
// LDS layout [128][64] f16 (128B rows) with 8-lane XOR swizzle (both-sides,
// rule #21): LDS chunk cc (16B) of row r holds global chunk cc ^ (r&7).
//  - staging: thread (row tid>>3, chunk tid&7) fetches global chunk
//    (tid&7)^((tid>>3)&7) -> each 8-lane group reads one contiguous 128B
//    global segment (coalescing preserved); gload dest stays linear.
//  - frag read: lane l, subtile s reads chunk ((s<<2)+(l>>4)) ^ (l&7)
//    (row&7 == l&7) -> per 8-lane issue group the 16B slots mod 128B are a
//    XOR-bijection -> all 32 banks, conflict-free (plain [128][64] would be
//    8-way conflicted, same mistake class as R1).
//
// Block mapping: two-level XCD patch swizzle (R8: FETCH 708->164 MB).
// MODE 0: C(f32) = A@B  (final GEMM)
// MODE 4: a-polar fused -> f16 (N=2048): val*sigmoid(|a|)/|a|, direct writes
// MODE 6: pair-product (N=4096): bn<2048: qsg = q*silu(g) -> Cv;
//         else kv = k*v -> Cv2. LDS-staged full-line writes.
// ---------------------------------------------------------------------------
template <int MODE>
__global__ __launch_bounds__(256, 2) void mfma_gemm_kernel(
    const f16_t* __restrict__ A, const f16_t* __restrict__ BT,
    void* __restrict__ Cv, void* __restrict__ Cv2, void* __restrict__ Cv3,
    int M, int N, int K)
{
    // K-loop: As = smem[0..8191], Bs = smem[8192..16383]  (each 128x64 f16).
    // MODE-6 pair epilogue reuses smem[0..8703] as [128][68] f16.
    __shared__ __align__(16) f16_t smem[2 * 128 * 64];
    f16_t* As = smem;
    f16_t* Bs = smem + 128 * 64;

    const int tid  = threadIdx.x;
    const int wave = tid >> 6;
    const int lane = tid & 63;

    // ---- two-level XCD patch swizzle -------------------------------------
    const int gx    = gridDim.x;
    const int gy    = gridDim.y;
    const int lid   = blockIdx.y * gx + blockIdx.x;
    const int xcd   = lid & 7;
    const int local = lid >> 3;
    const int rows  = gy >> 3;          // bm blocks per XCD stripe
    const int npn   = gx >> 3;          // bn patches
    const int patch = local >> 6;
    const int wi    = local & 63;
    const int pnp   = patch % npn;      // bn patch (fastest -> A-stripe reuse)
    const int pmp   = patch / npn;      // bm patch within stripe
    const int bm = (xcd * rows + pmp * 8 + (wi >> 3)) * 128;
    const int bn = (pnp * 8 + (wi & 7)) * 128;

    const int wm = (wave & 1) * 64;
    const int wn = (wave >> 1) * 64;

    // ---- staging: 8 lanes per row, XOR'd chunk ---------------------------
    const int sr = tid >> 3;                                  // row 0..31
    const int sc = (((tid & 7) ^ ((tid >> 3) & 7)) << 3);     // element col
    const f16_t* Ag = A  + (size_t)(bm + sr) * K + sc;
    const f16_t* Bg = BT + (size_t)(bn + sr) * K + sc;
    const size_t rs32 = (size_t)32 * K;
    f16_t* Al = As + tid * 8;           // + inst*2048
    f16_t* Bl = Bs + tid * 8;

    f32x4_t acc[4][4] = {};

    // ---- frag read: XOR'd chunk, conflict-free ---------------------------
    const int fm  = lane & 15;
    const int key = lane & 7;
    const int cs0 = ((lane >> 4) ^ key) << 3;        // subtile 0 element col
    const int cs1 = ((4 + (lane >> 4)) ^ key) << 3;  // subtile 1 element col

    for (int kt = 0; kt < K; kt += 64) {
        #pragma unroll
        for (int p = 0; p < 4; ++p) {
            gload16(Ag + p * rs32 + kt, Al + p * 2048);
            gload16(Bg + p * rs32 + kt, Bl + p * 2048);
        }
        __syncthreads();

        #pragma unroll
        for (int s = 0; s < 2; ++s) {
            const int cs = s ? cs1 : cs0;
            f16x8_t af[4], bfr[4];
            #pragma unroll
            for (int i = 0; i < 4; ++i)
                af[i] = *reinterpret_cast<const f16x8_t*>(&As[(wm + i * 16 + fm) * 64 + cs]);
            #pragma unroll
            for (int j = 0; j < 4; ++j)
                bfr[j] = *reinterpret_cast<const f16x8_t*>(&Bs[(wn + j * 16 + fm) * 64 + cs]);
            #pragma unroll
            for (int i = 0; i < 4; ++i)
                #pragma unroll
                for (int j = 0; j < 4; ++j)
                    acc[i][j] = __builtin_amdgcn_mfma_f32_16x16x32_f16(
                        af[i], bfr[j], acc[i][j], 0, 0, 0);
        }
        __syncthreads();
    }

    // epilogue: D row=(lane>>4)*4+reg, col=lane&15  (m89/m91-verified)
    const int erow = (lane >> 4) << 2;
    const int ecol = lane & 15;

    if (MODE == 6) {
        // ---- pair-product: stage to LDS, full-line copy out --------------
        const bool isQ = (bn < 2048);
        #pragma unroll
        for (int i = 0; i < 4; ++i) {
            #pragma unroll
            for (int j = 0; j < 4; ++j) {
                #pragma unroll
                for (int rg = 0; rg < 4; ++rg) {
                    const float val = acc[i][j][rg];
                    const float par = __shfl_xor(val, 1, 64);
                    if (!(lane & 1)) {
                        const float X = val, Y = par;
                        const float outv = isQ ? X * (Y / (1.0f + __expf(-Y)))
                                               : X * Y;
                        smem[(wm + i * 16 + erow + rg) * 68
                             + (wn >> 1) + j * 8 + (ecol >> 1)] = (f16_t)outv;
                    }
                }
            }
        }
        __syncthreads();
        f16_t* dstb = isQ ? (f16_t*)Cv : (f16_t*)Cv2;
        const int prow = tid >> 1;
        const int phal = (tid & 1) * 32;
        const f16_t* src = smem + prow * 68 + phal;
        f16_t* d = dstb + (size_t)(bm + prow) * DDIM + ((bn & 2047) >> 1) + phal;
        #pragma unroll
        for (int q = 0; q < 4; ++q)
            *reinterpret_cast<f16x8_t*>(d + q * 8) =
                *reinterpret_cast<const f16x8_t*>(src + q * 8);
        return;
    }

    #pragma unroll
    for (int i = 0; i < 4; ++i) {
        #pragma unroll
        for (int j = 0; j < 4; ++j) {
            const int row0 = bm + wm + i * 16 + erow;
            const int col  = bn + wn + j * 16 + ecol;
            #pragma unroll
            for (int rg = 0; rg < 4; ++rg) {
                const float val = acc[i][j][rg];
                if (MODE == 0) {
                    ((float*)Cv)[(size_t)(row0 + rg) * N + col] = val;
                } else {  // MODE 4: a-polar (N=2048), direct full-line writes
                    const float par = __shfl_xor(val, 1, 64);
                    const float re = (lane & 1) ? par : val;
                    const float im = (lane & 1) ? val : par;
                    const float r = sqrtf(re * re + im * im);
                    float outv;
                    if (r > 0.0f) {
                        const float sg = 1.0f / (1.0f + __expf(-r));
                        outv = val * (sg / r);
                    } else {
                        outv = (lane & 1) ? 0.0f : 0.5f;
                    }
                    ((f16_t*)Cv)[(size_t)(row0 + rg) * N + col] = (f16_t)outv;
                }
            }
        }
    }
}

// ---------------------------------------------------------------------------
// Scan phase 1 (x2 channels/thread): per-(b,chunk,d-pair) local scan;
// emit (A_prod, H_local) float4 per channel. a layout: [m][d] f16x2 (re,im).
// ---------------------------------------------------------------------------
__global__ __launch_bounds__(256) void scan1_kernel(
    const f16x2_t* __restrict__ a2, const f16_t* __restrict__ kvb,
    float4* __restrict__ state)
{
    const int t = blockIdx.x * 256 + threadIdx.x;   // B*NCHUNK*512
    const int d2 = (t & 511) << 1;
    const int c = (t >> 9) & (NCHUNK - 1);
    const int b = t >> 15;
    size_t base  = ((size_t)(b * SDIM + c * LCHUNK)) * DDIM + d2;
    float Ar0 = 1.0f, Ai0 = 0.0f, Hr0 = 0.0f, Hi0 = 0.0f;
    float Ar1 = 1.0f, Ai1 = 0.0f, Hr1 = 0.0f, Hi1 = 0.0f;
    for (int s = 0; s < LCHUNK; ++s) {
        const f16x4_t av = *reinterpret_cast<const f16x4_t*>(&a2[base]);   // 2 ch
        const f16x2_t kv2 = *reinterpret_cast<const f16x2_t*>(&kvb[base]);
        {
            const float ar = (float)av.x, ai = (float)av.y, kv = (float)kv2.x;
            const float hr = ar * Hr0 - ai * Hi0 + kv;
            const float hi = ar * Hi0 + ai * Hr0;
            Hr0 = hr; Hi0 = hi;
            const float nr = ar * Ar0 - ai * Ai0;
            const float ni = ar * Ai0 + ai * Ar0;
            Ar0 = nr; Ai0 = ni;
        }
        {
            const float ar = (float)av.z, ai = (float)av.w, kv = (float)kv2.y;
            const float hr = ar * Hr1 - ai * Hi1 + kv;
            const float hi = ar * Hi1 + ai * Hr1;
            Hr1 = hr; Hi1 = hi;
            const float nr = ar * Ar1 - ai * Ai1;
            const float ni = ar * Ai1 + ai * Ar1;
            Ar1 = nr; Ai1 = ni;
        }
        base += DDIM;
    }
    const size_t st = ((size_t)(b * NCHUNK + c)) * DDIM + d2;
    state[st]     = make_float4(Ar0, Ai0, Hr0, Hi0);
    state[st + 1] = make_float4(Ar1, Ai1, Hr1, Hi1);
}

// ---------------------------------------------------------------------------
// Scan phase 2: wave-parallel chunk combine. Lane c holds chunk c's state;
// 6-step Hillis-Steele inclusive scan of (A,H)∘, then exclusive-shift -> carry.
// ---------------------------------------------------------------------------
__global__ __launch_bounds__(256) void scan2_kernel(
    const float4* __restrict__ state, float2* __restrict__ carry)
{
    const int t = blockIdx.x * 256 + threadIdx.x;   // B*D*64 threads
    const int c = t & 63;            // chunk index = lane
    const int ch = t >> 6;           // channel: b*1024+d
    const int d = ch & 1023;
    const int b = ch >> 10;
    const size_t idx = ((size_t)(b * NCHUNK + c)) * DDIM + d;
    const float4 st = state[idx];
    float Ar = st.x, Ai = st.y, Hr = st.z, Hi = st.w;
    #pragma unroll
    for (int off = 1; off < 64; off <<= 1) {
        const float pAr = __shfl_up(Ar, off, 64);
        const float pAi = __shfl_up(Ai, off, 64);
        const float pHr = __shfl_up(Hr, off, 64);
        const float pHi = __shfl_up(Hi, off, 64);
        if (c >= off) {
            // compose(earlier=(pA,pH), current=(A,H)): A·pA, A·pH + H
            const float nHr = Ar * pHr - Ai * pHi + Hr;
            const float nHi = Ar * pHi + Ai * pHr + Hi;
            const float nAr = Ar * pAr - Ai * pAi;
            const float nAi = Ar * pAi + Ai * pAr;
            Ar = nAr; Ai = nAi; Hr = nHr; Hi = nHi;
        }
    }
    // exclusive prefix: carry into chunk c = inclusive H at chunk c-1
    const float eHr = __shfl_up(Hr, 1, 64);
    const float eHi = __shfl_up(Hi, 1, 64);
    carry[idx] = make_float2(c == 0 ? 0.0f : eHr, c == 0 ? 0.0f : eHi);
}

// ---------------------------------------------------------------------------
// Scan phase 3 (x2 channels/thread): re-scan with carry;
// y(f16) = qsg * Re(h), written IN-PLACE over kv.  (qsg = q*silu(g), fused
// in the mode-6 GEMM epilogue.)
// ---------------------------------------------------------------------------
__global__ __launch_bounds__(256) void scan3_kernel(
    const f16x2_t* __restrict__ a2, f16_t* __restrict__ kvb,
    const f16_t* __restrict__ qsgb, const float2* __restrict__ carry)
{
    const int t = blockIdx.x * 256 + threadIdx.x;   // B*NCHUNK*512
    const int d2 = (t & 511) << 1;
    const int c = (t >> 9) & (NCHUNK - 1);
    const int b = t >> 15;
    size_t base  = ((size_t)(b * SDIM + c * LCHUNK)) * DDIM + d2;
    const size_t st = ((size_t)(b * NCHUNK + c)) * DDIM + d2;
    const float2 h0a = carry[st];
    const float2 h0b = carry[st + 1];
    float Hr0 = h0a.x, Hi0 = h0a.y;
    float Hr1 = h0b.x, Hi1 = h0b.y;
    for (int s = 0; s < LCHUNK; ++s) {
        const f16x4_t av = *reinterpret_cast<const f16x4_t*>(&a2[base]);
        const f16x2_t kv2 = *reinterpret_cast<const f16x2_t*>(&kvb[base]);
        const f16x2_t qs2 = *reinterpret_cast<const f16x2_t*>(&qsgb[base]);
        f16x2_t y;
        {
            const float ar = (float)av.x, ai = (float)av.y, kv = (float)kv2.x;
            const float hr = ar * Hr0 - ai * Hi0 + kv;
            const float hi = ar * Hi0 + ai * Hr0;
            Hr0 = hr; Hi0 = hi;
            y.x = (f16_t)((float)qs2.x * hr);
        }
        {
            const float ar = (float)av.z, ai = (float)av.w, kv = (float)kv2.y;
            const float hr = ar * Hr1 - ai * Hi1 + kv;
            const float hi = ar * Hi1 + ai * Hr1;
            Hr1 = hr; Hi1 = hi;
            y.y = (f16_t)((float)qs2.y * hr);
        }
        *reinterpret_cast<f16x2_t*>(&kvb[base]) = y;
        base += DDIM;
    }
}

// ---------------------------------------------------------------------------
// kernel_launch
//
// Workspace layout (149 MB):
//   xn:  [SZ f16]   33.5MB — A operand; scan `state` (4MB) overlaps after death
//   kv:  [SZ f16]   33.5MB — kv=k*v (fused GEMM), then y (in-place in scan3)
//   a:   [SZ f16x2] 67MB   — interleaved (re,im) channel pairs
//   WT:  [7*WSZ f16] 14MB  — slots: 0..1=qg 2..3=kv 4..5=a (all interleaved),
//        6=o; `carry` (2MB) overlaps dead slot 0 after the projection GEMMs
// qsg (f16) lives in the first half of d_out until the final GEMM overwrites it.
// Launches: rmsnorm, wprep, GEMM6(N=4096), GEMM4(N=2048), scan1/2/3, GEMM0.
// ---------------------------------------------------------------------------
extern "C" void kernel_launch(void* const* d_in, const int* in_sizes, int n_in,
                              void* d_out, int out_size, void* d_ws, size_t ws_size,
                              hipStream_t stream)
{
    const float* x        = (const float*)d_in[0];
    const float* wq       = (const float*)d_in[1];
    const float* wk       = (const float*)d_in[2];
    const float* wv       = (const float*)d_in[3];
    const float* wa       = (const float*)d_in[4];
    const float* wg       = (const float*)d_in[5];
    const float* wo       = (const float*)d_in[6];
    const float* rms_scale= (const float*)d_in[7];
    float* out = (float*)d_out;

    const size_t SZ = (size_t)MROWS * DDIM;   // 16,777,216 elements
    const size_t WSZ = (size_t)DDIM * DDIM;   // 1,048,576
    char* ws = (char*)d_ws;
    f16_t*   xn   = (f16_t*)ws;                        // SZ f16
    f16_t*   kv   = (f16_t*)(ws + SZ * 2);             // SZ f16
    f16x2_t* abuf = (f16x2_t*)(ws + SZ * 4);           // SZ f16x2
    f16_t*   WT   = (f16_t*)(ws + SZ * 8);             // 7*WSZ f16
    f16_t* WTqg = WT;                // slots 0..1 (wq/wg interleaved)
    f16_t* WTkv = WT + 2 * WSZ;      // slots 2..3 (wk/wv interleaved)
    f16_t* WTa  = WT + 4 * WSZ;      // slots 4..5 (wa interleaved halves)
    f16_t* WTo  = WT + 6 * WSZ;      // slot 6
    float4* state = (float4*)xn;     // overlaps dead xn (4MB)
    float2* carry = (float2*)WT;     // overlaps dead WT slot 0 (2MB)

    f16_t* qsgb = (f16_t*)d_out;     // qsg f16 in first half of d_out

    const size_t needed = SZ * 8 + 7 * WSZ * 2;
    if (ws_size < needed) {
        const float marker = (float)(ws_size >> 20);
        fill_kernel<<<(out_size + 255) / 256, 256, 0, stream>>>(out, out_size, marker);
        return;
    }

    // 1. RMSNorm -> f16 xn
    rmsnorm_kernel<<<MROWS, 256, 0, stream>>>(x, rms_scale, xn);

    // 2. Weight prep (single launch)
    dim3 wgrid(64, 32, 4);
    wprep_kernel<<<wgrid, 256, 0, stream>>>(wq, wk, wv, wa, wg, wo, WT);

    // 3. Projections (split; both with patch swizzle)
    dim3 blk(256);
    dim3 g6(4 * DDIM / 128, MROWS / 128);     // (32,128): qg|kv pairs
    dim3 g4(2 * DDIM / 128, MROWS / 128);     // (16,128): a-polar
    mfma_gemm_kernel<6><<<g6, blk, 0, stream>>>(xn, WTqg, qsgb, kv, nullptr,
                                                MROWS, 4 * DDIM, DDIM);
    mfma_gemm_kernel<4><<<g4, blk, 0, stream>>>(xn, WTa, abuf, nullptr, nullptr,
                                                MROWS, 2 * DDIM, DDIM);

    // 4. chunked complex scan (x2-channel vectorized phases 1 & 3)
    const int nscan2 = BDIM * NCHUNK * 512;   // 131072 threads
    const int nscan  = BDIM * NCHUNK * DDIM;  // 262144 threads (phase 2)
    scan1_kernel<<<nscan2 / 256, 256, 0, stream>>>(abuf, kv, state);
    scan2_kernel<<<nscan / 256, 256, 0, stream>>>(state, carry);
    scan3_kernel<<<nscan2 / 256, 256, 0, stream>>>(abuf, kv, qsgb, carry);

    // 5. out = y @ wo   (y lives in kv buffer)
    dim3 g1(DDIM / 128, MROWS / 128);         // (8,128)
    mfma_gemm_kernel<0><<<g1, blk, 0, stream>>>(kv, WTo, out, nullptr, nullptr,
                                                MROWS, DDIM, DDIM);
}

// Round 12
// 388.119 us; speedup vs baseline: 1.1020x; 1.0083x over previous
//
#include <hip/hip_runtime.h>
#include <hip/hip_bf16.h>
#include <math.h>

// Problem constants (B,S,D) = (4,4096,1024)
#define BDIM 4
#define SDIM 4096
#define DDIM 1024
#define MROWS (BDIM*SDIM)      // 16384
#define EPS 1e-6f
#define NCHUNK 64              // chunks along S
#define LCHUNK 64              // chunk length (NCHUNK*LCHUNK == SDIM)

typedef _Float16 f16_t;
typedef _Float16 f16x2_t __attribute__((ext_vector_type(2)));
typedef _Float16 f16x4_t __attribute__((ext_vector_type(4)));
typedef _Float16 f16x8_t __attribute__((ext_vector_type(8)));     // MFMA A/B frag (4 VGPRs)
typedef float    f32x4_t __attribute__((ext_vector_type(4)));     // MFMA C/D frag

// async global->LDS, 16B per lane (dest = wave-uniform base + lane*16)
__device__ __forceinline__ void gload16(const void* g, void* l) {
    __builtin_amdgcn_global_load_lds(
        (const __attribute__((address_space(1))) unsigned int*)g,
        (__attribute__((address_space(3))) unsigned int*)l, 16, 0, 0);
}

// ---------------------------------------------------------------------------
// Guard-fail fill (encodes ws_size MB as output on too-small workspace)
// ---------------------------------------------------------------------------
__global__ __launch_bounds__(256) void fill_kernel(float* __restrict__ out,
                                                   int n, float val)
{
    const int i = blockIdx.x * 256 + threadIdx.x;
    if (i < n) out[i] = val;
}

// ---------------------------------------------------------------------------
// Fused prep (R11): rmsnorm + all weight transposes in ONE launch so the two
// independent memory-bound phases run CONCURRENTLY (serial cost ~27 us,
// combined BW-bound ~21 us). 1-D grid of 8192+16384 blocks:
//   bid <  8192 : weight prep, decoded (bx,by,z) from old (64,32,4) grid
//     z=0: (wq,wg) pair-interleaved -> WT slots 0..1
//     z=1: (wk,wv) pair-interleaved -> WT slots 2..3
//     z=2: wo plain transpose       -> WT slot 6
//     z=3: wa half-interleaved      -> WT slots 4..5
//   bid >= 8192 : RMSNorm row (bid-8192), f32 x -> f16 xn
// Both paths use 256 threads; no cross-path barriers (early returns happen
// before any __syncthreads on their path).
// ---------------------------------------------------------------------------
__global__ __launch_bounds__(256) void prep_kernel(
    const float* __restrict__ x, const float* __restrict__ rms_scale,
    f16_t* __restrict__ xn,
    const float* __restrict__ wq, const float* __restrict__ wk,
    const float* __restrict__ wv, const float* __restrict__ wa,
    const float* __restrict__ wg, const float* __restrict__ wo,
    f16_t* __restrict__ WT)
{
    const int bid = blockIdx.x;
    const int tid = threadIdx.x;

    if (bid >= 8192) {
        // ---------------- RMSNorm path ------------------------------------
        const int row = bid - 8192;
        const float4 v = reinterpret_cast<const float4*>(x + (size_t)row * DDIM)[tid];
        float ss = v.x*v.x + v.y*v.y + v.z*v.z + v.w*v.w;
        #pragma unroll
        for (int off = 32; off > 0; off >>= 1)
            ss += __shfl_down(ss, off, 64);
        __shared__ float red[4];
        if ((tid & 63) == 0) red[tid >> 6] = ss;
        __syncthreads();
        ss = red[0] + red[1] + red[2] + red[3];
        const float inv = rsqrtf(ss * (1.0f / DDIM) + EPS);
        const float4 sc = reinterpret_cast<const float4*>(rms_scale)[tid];
        f16x4_t o;
        o.x = (f16_t)(v.x * inv * sc.x);
        o.y = (f16_t)(v.y * inv * sc.y);
        o.z = (f16_t)(v.z * inv * sc.z);
        o.w = (f16_t)(v.w * inv * sc.w);
        reinterpret_cast<f16x4_t*>(xn + (size_t)row * DDIM)[tid] = o;
        return;
    }

    // ---------------- weight-prep path ------------------------------------
    const size_t WSZ = (size_t)DDIM * DDIM;
    const int z  = bid >> 11;            // 0..3
    const int rem = bid & 2047;
    const int by = rem >> 6;             // 0..31
    const int bx = rem & 63;             // 0..63
    __shared__ float t0[32][33];
    __shared__ float t1[32][33];
    const int kb = by * 32;
    const int r  = tid >> 3;
    const int c0 = (tid & 7) << 2;

    if (z == 3) {
        // wa: W[K][2048] -> WT[n][K], row n <- col (n>>1) + (n&1)*1024
        const int K = DDIM, N = 2 * DDIM;
        const int nb = bx * 32;
        const int base = (c0 < 16) ? ((nb >> 1) + c0) : (DDIM + (nb >> 1) + c0 - 16);
        const float4 v = *reinterpret_cast<const float4*>(&wa[(size_t)(kb + r) * N + base]);
        t0[r][c0 + 0] = v.x; t0[r][c0 + 1] = v.y; t0[r][c0 + 2] = v.z; t0[r][c0 + 3] = v.w;
        __syncthreads();
        const int ctile = (r >> 1) + (r & 1) * 16;
        f16x4_t o;
        o.x = (f16_t)t0[c0 + 0][ctile];
        o.y = (f16_t)t0[c0 + 1][ctile];
        o.z = (f16_t)t0[c0 + 2][ctile];
        o.w = (f16_t)t0[c0 + 3][ctile];
        *reinterpret_cast<f16x4_t*>(&WT[4 * WSZ + (size_t)(nb + r) * K + kb + c0]) = o;
        return;
    }
    if (bx >= 32) return;
    const int nb = bx * 32;
    const int K = DDIM, N = DDIM;
    if (z == 2) {
        // wo plain transpose -> slot 6
        const float4 v = *reinterpret_cast<const float4*>(&wo[(size_t)(kb + r) * N + nb + c0]);
        t0[r][c0 + 0] = v.x; t0[r][c0 + 1] = v.y; t0[r][c0 + 2] = v.z; t0[r][c0 + 3] = v.w;
        __syncthreads();
        f16x4_t o;
        o.x = (f16_t)t0[c0 + 0][r];
        o.y = (f16_t)t0[c0 + 1][r];
        o.z = (f16_t)t0[c0 + 2][r];
        o.w = (f16_t)t0[c0 + 3][r];
        *reinterpret_cast<f16x4_t*>(&WT[6 * WSZ + (size_t)(nb + r) * K + kb + c0]) = o;
        return;
    }
    // z=0/1: pair-interleave (W0,W1): WT[2n][k]=W0[k][n], WT[2n+1][k]=W1[k][n]
    const float* W0 = (z == 0) ? wq : wk;
    const float* W1 = (z == 0) ? wg : wv;
    f16_t* dst = WT + (size_t)(z * 2) * WSZ;
    const float4 v0 = *reinterpret_cast<const float4*>(&W0[(size_t)(kb + r) * N + nb + c0]);
    const float4 v1 = *reinterpret_cast<const float4*>(&W1[(size_t)(kb + r) * N + nb + c0]);
    t0[r][c0 + 0] = v0.x; t0[r][c0 + 1] = v0.y; t0[r][c0 + 2] = v0.z; t0[r][c0 + 3] = v0.w;
    t1[r][c0 + 0] = v1.x; t1[r][c0 + 1] = v1.y; t1[r][c0 + 2] = v1.z; t1[r][c0 + 3] = v1.w;
    __syncthreads();
    const int rr  = tid >> 2;        // output row in block: 0..63
    const int cc0 = (tid & 3) << 3;  // 0,8,16,24
    const int n   = rr >> 1;         // source col within tile
    f16x8_t o;
    if (rr & 1) {
        #pragma unroll
        for (int e = 0; e < 8; ++e) o[e] = (f16_t)t1[cc0 + e][n];
    } else {
        #pragma unroll
        for (int e = 0; e < 8; ++e) o[e] = (f16_t)t0[cc0 + e][n];
    }
    *reinterpret_cast<f16x8_t*>(&dst[(size_t)(2 * nb + rr) * K + kb + cc0]) = o;
}

// ---------------------------------------------------------------------------
// fp16 MFMA GEMM: C[M,N] = A[M,K] @ BT[N,K]^T
// 128x128 tile, 256 threads = 4 waves, each wave 64x64 (4x4 MFMA tiles).
//
// BK=64 (R10-proven: GEMM6 192->168 us, MfmaUtil 33->38.4): same 2-barrier
// m97 structure, half the iterations vs BK=32 -> barrier-drain time halves.
// LDS 32 KB (m132's regression was BK=128/64KB; this stays clear).
//
// LDS layout [128][64] f16 (128B rows) with 8-lane XOR swizzle (both-sides,
// rule #21): LDS chunk cc (16B) of row r holds global chunk cc ^ (r&7).
//  - staging: thread (row tid>>3, chunk tid&7) fetches global chunk
//    (tid&7)^((tid>>3)&7) -> each 8-lane group reads one contiguous 128B
//    global segment; gload dest stays linear.
//  - frag read: lane l, subtile s reads chunk ((s<<2)+(l>>4)) ^ (l&7)
//    -> per 8-lane issue group a XOR-bijection over all 32 banks ->
//    conflict-free (verified: SQ_LDS_BANK_CONFLICT = 0).
//
// Block mapping: two-level XCD patch swizzle (R8: FETCH 708->164 MB).
// MODE 0: C(f32) = A@B  (final GEMM)
// MODE 4: a-polar fused -> f16 (N=2048): val*sigmoid(|a|)/|a|, direct writes
// MODE 6: pair-product (N=4096): bn<2048: qsg = q*silu(g) -> Cv;
//         else kv = k*v -> Cv2. LDS-staged full-line writes.
// ---------------------------------------------------------------------------
template <int MODE>
__global__ __launch_bounds__(256, 2) void mfma_gemm_kernel(
    const f16_t* __restrict__ A, const f16_t* __restrict__ BT,
    void* __restrict__ Cv, void* __restrict__ Cv2, void* __restrict__ Cv3,
    int M, int N, int K)
{
    // K-loop: As = smem[0..8191], Bs = smem[8192..16383]  (each 128x64 f16).
    // MODE-6 pair epilogue reuses smem[0..8703] as [128][68] f16.
    __shared__ __align__(16) f16_t smem[2 * 128 * 64];
    f16_t* As = smem;
    f16_t* Bs = smem + 128 * 64;

    const int tid  = threadIdx.x;
    const int wave = tid >> 6;
    const int lane = tid & 63;

    // ---- two-level XCD patch swizzle -------------------------------------
    const int gx    = gridDim.x;
    const int gy    = gridDim.y;
    const int lid   = blockIdx.y * gx + blockIdx.x;
    const int xcd   = lid & 7;
    const int local = lid >> 3;
    const int rows  = gy >> 3;          // bm blocks per XCD stripe
    const int npn   = gx >> 3;          // bn patches
    const int patch = local >> 6;
    const int wi    = local & 63;
    const int pnp   = patch % npn;      // bn patch (fastest -> A-stripe reuse)
    const int pmp   = patch / npn;      // bm patch within stripe
    const int bm = (xcd * rows + pmp * 8 + (wi >> 3)) * 128;
    const int bn = (pnp * 8 + (wi & 7)) * 128;

    const int wm = (wave & 1) * 64;
    const int wn = (wave >> 1) * 64;

    // ---- staging: 8 lanes per row, XOR'd chunk ---------------------------
    const int sr = tid >> 3;                                  // row 0..31
    const int sc = (((tid & 7) ^ ((tid >> 3) & 7)) << 3);     // element col
    const f16_t* Ag = A  + (size_t)(bm + sr) * K + sc;
    const f16_t* Bg = BT + (size_t)(bn + sr) * K + sc;
    const size_t rs32 = (size_t)32 * K;
    f16_t* Al = As + tid * 8;           // + inst*2048
    f16_t* Bl = Bs + tid * 8;

    f32x4_t acc[4][4] = {};

    // ---- frag read: XOR'd chunk, conflict-free ---------------------------
    const int fm  = lane & 15;
    const int key = lane & 7;
    const int cs0 = ((lane >> 4) ^ key) << 3;        // subtile 0 element col
    const int cs1 = ((4 + (lane >> 4)) ^ key) << 3;  // subtile 1 element col

    for (int kt = 0; kt < K; kt += 64) {
        #pragma unroll
        for (int p = 0; p < 4; ++p) {
            gload16(Ag + p * rs32 + kt, Al + p * 2048);
            gload16(Bg + p * rs32 + kt, Bl + p * 2048);
        }
        __syncthreads();

        #pragma unroll
        for (int s = 0; s < 2; ++s) {
            const int cs = s ? cs1 : cs0;
            f16x8_t af[4], bfr[4];
            #pragma unroll
            for (int i = 0; i < 4; ++i)
                af[i] = *reinterpret_cast<const f16x8_t*>(&As[(wm + i * 16 + fm) * 64 + cs]);
            #pragma unroll
            for (int j = 0; j < 4; ++j)
                bfr[j] = *reinterpret_cast<const f16x8_t*>(&Bs[(wn + j * 16 + fm) * 64 + cs]);
            #pragma unroll
            for (int i = 0; i < 4; ++i)
                #pragma unroll
                for (int j = 0; j < 4; ++j)
                    acc[i][j] = __builtin_amdgcn_mfma_f32_16x16x32_f16(
                        af[i], bfr[j], acc[i][j], 0, 0, 0);
        }
        __syncthreads();
    }

    // epilogue: D row=(lane>>4)*4+reg, col=lane&15  (m89/m91-verified)
    const int erow = (lane >> 4) << 2;
    const int ecol = lane & 15;

    if (MODE == 6) {
        // ---- pair-product: stage to LDS, full-line copy out --------------
        const bool isQ = (bn < 2048);
        #pragma unroll
        for (int i = 0; i < 4; ++i) {
            #pragma unroll
            for (int j = 0; j < 4; ++j) {
                #pragma unroll
                for (int rg = 0; rg < 4; ++rg) {
                    const float val = acc[i][j][rg];
                    const float par = __shfl_xor(val, 1, 64);
                    if (!(lane & 1)) {
                        const float X = val, Y = par;
                        const float outv = isQ ? X * (Y / (1.0f + __expf(-Y)))
                                               : X * Y;
                        smem[(wm + i * 16 + erow + rg) * 68
                             + (wn >> 1) + j * 8 + (ecol >> 1)] = (f16_t)outv;
                    }
                }
            }
        }
        __syncthreads();
        f16_t* dstb = isQ ? (f16_t*)Cv : (f16_t*)Cv2;
        const int prow = tid >> 1;
        const int phal = (tid & 1) * 32;
        const f16_t* src = smem + prow * 68 + phal;
        f16_t* d = dstb + (size_t)(bm + prow) * DDIM + ((bn & 2047) >> 1) + phal;
        #pragma unroll
        for (int q = 0; q < 4; ++q)
            *reinterpret_cast<f16x8_t*>(d + q * 8) =
                *reinterpret_cast<const f16x8_t*>(src + q * 8);
        return;
    }

    #pragma unroll
    for (int i = 0; i < 4; ++i) {
        #pragma unroll
        for (int j = 0; j < 4; ++j) {
            const int row0 = bm + wm + i * 16 + erow;
            const int col  = bn + wn + j * 16 + ecol;
            #pragma unroll
            for (int rg = 0; rg < 4; ++rg) {
                const float val = acc[i][j][rg];
                if (MODE == 0) {
                    ((float*)Cv)[(size_t)(row0 + rg) * N + col] = val;
                } else {  // MODE 4: a-polar (N=2048), direct full-line writes
                    const float par = __shfl_xor(val, 1, 64);
                    const float re = (lane & 1) ? par : val;
                    const float im = (lane & 1) ? val : par;
                    const float r = sqrtf(re * re + im * im);
                    float outv;
                    if (r > 0.0f) {
                        const float sg = 1.0f / (1.0f + __expf(-r));
                        outv = val * (sg / r);
                    } else {
                        outv = (lane & 1) ? 0.0f : 0.5f;
                    }
                    ((f16_t*)Cv)[(size_t)(row0 + rg) * N + col] = (f16_t)outv;
                }
            }
        }
    }
}

// ---------------------------------------------------------------------------
// Scan phase 1 (x2 channels/thread): per-(b,chunk,d-pair) local scan;
// emit (A_prod, H_local) float4 per channel. a layout: [m][d] f16x2 (re,im).
// ---------------------------------------------------------------------------
__global__ __launch_bounds__(256) void scan1_kernel(
    const f16x2_t* __restrict__ a2, const f16_t* __restrict__ kvb,
    float4* __restrict__ state)
{
    const int t = blockIdx.x * 256 + threadIdx.x;   // B*NCHUNK*512
    const int d2 = (t & 511) << 1;
    const int c = (t >> 9) & (NCHUNK - 1);
    const int b = t >> 15;
    size_t base  = ((size_t)(b * SDIM + c * LCHUNK)) * DDIM + d2;
    float Ar0 = 1.0f, Ai0 = 0.0f, Hr0 = 0.0f, Hi0 = 0.0f;
    float Ar1 = 1.0f, Ai1 = 0.0f, Hr1 = 0.0f, Hi1 = 0.0f;
    for (int s = 0; s < LCHUNK; ++s) {
        const f16x4_t av = *reinterpret_cast<const f16x4_t*>(&a2[base]);   // 2 ch
        const f16x2_t kv2 = *reinterpret_cast<const f16x2_t*>(&kvb[base]);
        {
            const float ar = (float)av.x, ai = (float)av.y, kv = (float)kv2.x;
            const float hr = ar * Hr0 - ai * Hi0 + kv;
            const float hi = ar * Hi0 + ai * Hr0;
            Hr0 = hr; Hi0 = hi;
            const float nr = ar * Ar0 - ai * Ai0;
            const float ni = ar * Ai0 + ai * Ar0;
            Ar0 = nr; Ai0 = ni;
        }
        {
            const float ar = (float)av.z, ai = (float)av.w, kv = (float)kv2.y;
            const float hr = ar * Hr1 - ai * Hi1 + kv;
            const float hi = ar * Hi1 + ai * Hr1;
            Hr1 = hr; Hi1 = hi;
            const float nr = ar * Ar1 - ai * Ai1;
            const float ni = ar * Ai1 + ai * Ar1;
            Ar1 = nr; Ai1 = ni;
        }
        base += DDIM;
    }
    const size_t st = ((size_t)(b * NCHUNK + c)) * DDIM + d2;
    state[st]     = make_float4(Ar0, Ai0, Hr0, Hi0);
    state[st + 1] = make_float4(Ar1, Ai1, Hr1, Hi1);
}

// ---------------------------------------------------------------------------
// Scan phase 2: wave-parallel chunk combine. Lane c holds chunk c's state;
// 6-step Hillis-Steele inclusive scan of (A,H)∘, then exclusive-shift -> carry.
// ---------------------------------------------------------------------------
__global__ __launch_bounds__(256) void scan2_kernel(
    const float4* __restrict__ state, float2* __restrict__ carry)
{
    const int t = blockIdx.x * 256 + threadIdx.x;   // B*D*64 threads
    const int c = t & 63;            // chunk index = lane
    const int ch = t >> 6;           // channel: b*1024+d
    const int d = ch & 1023;
    const int b = ch >> 10;
    const size_t idx = ((size_t)(b * NCHUNK + c)) * DDIM + d;
    const float4 st = state[idx];
    float Ar = st.x, Ai = st.y, Hr = st.z, Hi = st.w;
    #pragma unroll
    for (int off = 1; off < 64; off <<= 1) {
        const float pAr = __shfl_up(Ar, off, 64);
        const float pAi = __shfl_up(Ai, off, 64);
        const float pHr = __shfl_up(Hr, off, 64);
        const float pHi = __shfl_up(Hi, off, 64);
        if (c >= off) {
            // compose(earlier=(pA,pH), current=(A,H)): A·pA, A·pH + H
            const float nHr = Ar * pHr - Ai * pHi + Hr;
            const float nHi = Ar * pHi + Ai * pHr + Hi;
            const float nAr = Ar * pAr - Ai * pAi;
            const float nAi = Ar * pAi + Ai * pAr;
            Ar = nAr; Ai = nAi; Hr = nHr; Hi = nHi;
        }
    }
    // exclusive prefix: carry into chunk c = inclusive H at chunk c-1
    const float eHr = __shfl_up(Hr, 1, 64);
    const float eHi = __shfl_up(Hi, 1, 64);
    carry[idx] = make_float2(c == 0 ? 0.0f : eHr, c == 0 ? 0.0f : eHi);
}

// ---------------------------------------------------------------------------
// Scan phase 3 (x2 channels/thread): re-scan with carry;
// y(f16) = qsg * Re(h), written IN-PLACE over kv.  (qsg = q*silu(g), fused
// in the mode-6 GEMM epilogue.)
// ---------------------------------------------------------------------------
__global__ __launch_bounds__(256) void scan3_kernel(
    const f16x2_t* __restrict__ a2, f16_t* __restrict__ kvb,
    const f16_t* __restrict__ qsgb, const float2* __restrict__ carry)
{
    const int t = blockIdx.x * 256 + threadIdx.x;   // B*NCHUNK*512
    const int d2 = (t & 511) << 1;
    const int c = (t >> 9) & (NCHUNK - 1);
    const int b = t >> 15;
    size_t base  = ((size_t)(b * SDIM + c * LCHUNK)) * DDIM + d2;
    const size_t st = ((size_t)(b * NCHUNK + c)) * DDIM + d2;
    const float2 h0a = carry[st];
    const float2 h0b = carry[st + 1];
    float Hr0 = h0a.x, Hi0 = h0a.y;
    float Hr1 = h0b.x, Hi1 = h0b.y;
    for (int s = 0; s < LCHUNK; ++s) {
        const f16x4_t av = *reinterpret_cast<const f16x4_t*>(&a2[base]);
        const f16x2_t kv2 = *reinterpret_cast<const f16x2_t*>(&kvb[base]);
        const f16x2_t qs2 = *reinterpret_cast<const f16x2_t*>(&qsgb[base]);
        f16x2_t y;
        {
            const float ar = (float)av.x, ai = (float)av.y, kv = (float)kv2.x;
            const float hr = ar * Hr0 - ai * Hi0 + kv;
            const float hi = ar * Hi0 + ai * Hr0;
            Hr0 = hr; Hi0 = hi;
            y.x = (f16_t)((float)qs2.x * hr);
        }
        {
            const float ar = (float)av.z, ai = (float)av.w, kv = (float)kv2.y;
            const float hr = ar * Hr1 - ai * Hi1 + kv;
            const float hi = ar * Hi1 + ai * Hr1;
            Hr1 = hr; Hi1 = hi;
            y.y = (f16_t)((float)qs2.y * hr);
        }
        *reinterpret_cast<f16x2_t*>(&kvb[base]) = y;
        base += DDIM;
    }
}

// ---------------------------------------------------------------------------
// kernel_launch
//
// Workspace layout (149 MB):
//   xn:  [SZ f16]   33.5MB — A operand; scan `state` (4MB) overlaps after death
//   kv:  [SZ f16]   33.5MB — kv=k*v (fused GEMM), then y (in-place in scan3)
//   a:   [SZ f16x2] 67MB   — interleaved (re,im) channel pairs
//   WT:  [7*WSZ f16] 14MB  — slots: 0..1=qg 2..3=kv 4..5=a (all interleaved),
//        6=o; `carry` (2MB) overlaps dead slot 0 after the projection GEMMs
// qsg (f16) lives in the first half of d_out until the final GEMM overwrites it.
// Launches: prep(fused rmsnorm+wprep), GEMM6, GEMM4, scan1/2/3, GEMM0.
// ---------------------------------------------------------------------------
extern "C" void kernel_launch(void* const* d_in, const int* in_sizes, int n_in,
                              void* d_out, int out_size, void* d_ws, size_t ws_size,
                              hipStream_t stream)
{
    const float* x        = (const float*)d_in[0];
    const float* wq       = (const float*)d_in[1];
    const float* wk       = (const float*)d_in[2];
    const float* wv       = (const float*)d_in[3];
    const float* wa       = (const float*)d_in[4];
    const float* wg       = (const float*)d_in[5];
    const float* wo       = (const float*)d_in[6];
    const float* rms_scale= (const float*)d_in[7];
    float* out = (float*)d_out;

    const size_t SZ = (size_t)MROWS * DDIM;   // 16,777,216 elements
    const size_t WSZ = (size_t)DDIM * DDIM;   // 1,048,576
    char* ws = (char*)d_ws;
    f16_t*   xn   = (f16_t*)ws;                        // SZ f16
    f16_t*   kv   = (f16_t*)(ws + SZ * 2);             // SZ f16
    f16x2_t* abuf = (f16x2_t*)(ws + SZ * 4);           // SZ f16x2
    f16_t*   WT   = (f16_t*)(ws + SZ * 8);             // 7*WSZ f16
    f16_t* WTqg = WT;                // slots 0..1 (wq/wg interleaved)
    f16_t* WTa  = WT + 4 * WSZ;      // slots 4..5 (wa interleaved halves)
    f16_t* WTo  = WT + 6 * WSZ;      // slot 6
    float4* state = (float4*)xn;     // overlaps dead xn (4MB)
    float2* carry = (float2*)WT;     // overlaps dead WT slot 0 (2MB)

    f16_t* qsgb = (f16_t*)d_out;     // qsg f16 in first half of d_out

    const size_t needed = SZ * 8 + 7 * WSZ * 2;
    if (ws_size < needed) {
        const float marker = (float)(ws_size >> 20);
        fill_kernel<<<(out_size + 255) / 256, 256, 0, stream>>>(out, out_size, marker);
        return;
    }

    // 1. Fused prep: weight transposes (blocks 0..8191) + RMSNorm (8192..24575)
    prep_kernel<<<8192 + MROWS, 256, 0, stream>>>(x, rms_scale, xn,
                                                  wq, wk, wv, wa, wg, wo, WT);

    // 2. Projections (split; both with patch swizzle)
    dim3 blk(256);
    dim3 g6(4 * DDIM / 128, MROWS / 128);     // (32,128): qg|kv pairs
    dim3 g4(2 * DDIM / 128, MROWS / 128);     // (16,128): a-polar
    mfma_gemm_kernel<6><<<g6, blk, 0, stream>>>(xn, WTqg, qsgb, kv, nullptr,
                                                MROWS, 4 * DDIM, DDIM);
    mfma_gemm_kernel<4><<<g4, blk, 0, stream>>>(xn, WTa, abuf, nullptr, nullptr,
                                                MROWS, 2 * DDIM, DDIM);

    // 3. chunked complex scan (x2-channel vectorized phases 1 & 3)
    const int nscan2 = BDIM * NCHUNK * 512;   // 131072 threads
    const int nscan  = BDIM * NCHUNK * DDIM;  // 262144 threads (phase 2)
    scan1_kernel<<<nscan2 / 256, 256, 0, stream>>>(abuf, kv, state);
    scan2_kernel<<<nscan / 256, 256, 0, stream>>>(state, carry);
    scan3_kernel<<<nscan2 / 256, 256, 0, stream>>>(abuf, kv, qsgb, carry);

    // 4. out = y @ wo   (y lives in kv buffer)
    dim3 g1(DDIM / 128, MROWS / 128);         // (8,128)
    mfma_gemm_kernel<0><<<g1, blk, 0, stream>>>(kv, WTo, out, nullptr, nullptr,
                                                MROWS, DDIM, DDIM);
}